// Round 8
// baseline (206.449 us; speedup 1.0000x reference)
//
#include <hip/hip_runtime.h>
#include <hip/hip_bf16.h>

#define B_  2
#define L_  2048
#define D_  1024
#define H_  16
#define DH_ 64
#define M_  (B_*L_)     // 4096
#define N1_ (3*D_)      // 3072

typedef __bf16 bf16x8 __attribute__((ext_vector_type(8)));
typedef float  f32x4  __attribute__((ext_vector_type(4)));
typedef unsigned short ushort_t;
typedef unsigned short ushort8_t __attribute__((ext_vector_type(8)));
typedef unsigned int   uintx2    __attribute__((ext_vector_type(2)));

#define MFMA16(a,b,c) __builtin_amdgcn_mfma_f32_16x16x32_bf16((a),(b),(c),0,0,0)

__device__ __forceinline__ float4 ld4(const float* p) { return *(const float4*)p; }

__device__ __forceinline__ ushort_t f2bf(float f) {
    union { float f; unsigned int u; } v; v.f = f;
    unsigned int r = (v.u + 0x7FFFu + ((v.u >> 16) & 1u)) >> 16;
    return (ushort_t)r;
}
__device__ __forceinline__ float bf2f(ushort_t u) {
    union { unsigned int u; float f; } v; v.u = ((unsigned int)u) << 16;
    return v.f;
}
// v_exp_f32 computes 2^x
__device__ __forceinline__ float exp2_(float x) {
    float r; asm("v_exp_f32 %0, %1" : "=v"(r) : "v"(x)); return r;
}
// packed f32 pair -> bf16 pair (lo = a, hi = b)
__device__ __forceinline__ unsigned cvtpk(float a, float b) {
    unsigned r; asm("v_cvt_pk_bf16_f32 %0, %1, %2" : "=v"(r) : "v"(a), "v"(b)); return r;
}
// pull float from lane (byte_addr = src_lane*4)
__device__ __forceinline__ float bperm_f(int byte_addr, float v) {
    union { float f; int i; } u; u.f = v;
    u.i = __builtin_amdgcn_ds_bpermute(byte_addr, u.i);
    return u.f;
}
// async global->LDS, 16B per lane; LDS dest = wave-uniform base + lane*16
__device__ __forceinline__ void gload16(const ushort_t* g, ushort_t* l) {
    __builtin_amdgcn_global_load_lds(
        (const __attribute__((address_space(1))) unsigned int*)g,
        (__attribute__((address_space(3))) unsigned int*)l, 16, 0, 0);
}

// ---------------------------------------------------------------------------
// x fp32 -> bf16, elementwise, 8/thread
// ---------------------------------------------------------------------------
__global__ __launch_bounds__(256)
void convert_x(const float* __restrict__ in, ushort_t* __restrict__ out)
{
    int i = (blockIdx.x * 256 + threadIdx.x) * 8;
    float4 a = ld4(in + i), b = ld4(in + i + 4);
    ushort8_t o;
    o[0] = f2bf(a.x); o[1] = f2bf(a.y); o[2] = f2bf(a.z); o[3] = f2bf(a.w);
    o[4] = f2bf(b.x); o[5] = f2bf(b.y); o[6] = f2bf(b.z); o[7] = f2bf(b.w);
    *(ushort8_t*)(out + i) = o;
}

// ---------------------------------------------------------------------------
// W fp32 [1024][N] -> bf16 W^T [N][1024], 64x64 LDS tiles
// ---------------------------------------------------------------------------
template<int N>
__global__ __launch_bounds__(256)
void transpose_w(const float* __restrict__ in, ushort_t* __restrict__ out)
{
    __shared__ float vs[64][65];
    const int nt = blockIdx.x, kt = blockIdx.y, t = threadIdx.x;
    #pragma unroll
    for (int i = 0; i < 4; ++i) {
        int idx = t + 256 * i;
        int row = idx >> 4, c4 = idx & 15;
        float4 x4 = ld4(in + (size_t)(kt * 64 + row) * N + nt * 64 + c4 * 4);
        vs[row][c4*4+0] = x4.x; vs[row][c4*4+1] = x4.y;
        vs[row][c4*4+2] = x4.z; vs[row][c4*4+3] = x4.w;
    }
    __syncthreads();
    #pragma unroll
    for (int i = 0; i < 16; ++i) {
        int idx = t + 256 * i;
        int nc = idx >> 6, kc = idx & 63;
        out[(size_t)(nt * 64 + nc) * 1024 + kt * 64 + kc] = f2bf(vs[kc][nc]);
    }
}

// ---------------------------------------------------------------------------
// bf16 MFMA GEMM, m97 structure. EPI 0: fp32 C. EPI 1: QKV scatter with
// V written TRANSPOSED (vt [bh][64 d][L]) so transpose_v is not needed.
// ---------------------------------------------------------------------------
template<int EPI>
__global__ __launch_bounds__(256)
void bgemm(const ushort_t* __restrict__ A, const ushort_t* __restrict__ Bt,
           float* __restrict__ Cf,
           ushort_t* __restrict__ Qo, ushort_t* __restrict__ Ko, ushort_t* __restrict__ Vo)
{
    constexpr int K = 1024;
    __shared__ ushort_t As[128 * 64];
    __shared__ ushort_t Bs[128 * 64];
    const int t  = threadIdx.x;
    const int l  = t & 63, w = t >> 6;
    const int g  = l >> 4, ln = l & 15;
    const int wr = w >> 1, wc = w & 1;
    const int m0 = blockIdx.y * 128, n0 = blockIdx.x * 128;

    const int srow = w * 8 + (l >> 3);
    const int sch  = (l & 7) ^ (l >> 3);
    const ushort_t* Ag = A  + ((size_t)(m0 + srow)) * K + sch * 8;
    const ushort_t* Bg = Bt + ((size_t)(n0 + srow)) * K + sch * 8;

    f32x4 acc[4][4];
    #pragma unroll
    for (int mi = 0; mi < 4; ++mi)
        #pragma unroll
        for (int nj = 0; nj < 4; ++nj) acc[mi][nj] = f32x4{0.f, 0.f, 0.f, 0.f};

    for (int kt = 0; kt < K / 64; ++kt) {
        #pragma unroll
        for (int i = 0; i < 4; ++i)
            gload16(Ag + (size_t)i * 32 * K + kt * 64, &As[i * 2048 + w * 512]);
        #pragma unroll
        for (int i = 0; i < 4; ++i)
            gload16(Bg + (size_t)i * 32 * K + kt * 64, &Bs[i * 2048 + w * 512]);
        __syncthreads();

        #pragma unroll
        for (int kk = 0; kk < 2; ++kk) {
            bf16x8 af[4], bfv[4];
            #pragma unroll
            for (int mi = 0; mi < 4; ++mi) {
                int row  = 64 * wr + 16 * mi + ln;
                int phys = (4 * kk + g) ^ (ln & 7);
                af[mi] = *(const bf16x8*)&As[row * 64 + phys * 8];
            }
            #pragma unroll
            for (int nj = 0; nj < 4; ++nj) {
                int row  = 64 * wc + 16 * nj + ln;
                int phys = (4 * kk + g) ^ (ln & 7);
                bfv[nj] = *(const bf16x8*)&Bs[row * 64 + phys * 8];
            }
            #pragma unroll
            for (int mi = 0; mi < 4; ++mi)
                #pragma unroll
                for (int nj = 0; nj < 4; ++nj)
                    acc[mi][nj] = MFMA16(af[mi], bfv[nj], acc[mi][nj]);
        }
        __syncthreads();
    }

    if (EPI == 0) {
        #pragma unroll
        for (int mi = 0; mi < 4; ++mi) {
            #pragma unroll
            for (int nj = 0; nj < 4; ++nj) {
                int n = n0 + 64 * wc + 16 * nj + ln;
                #pragma unroll
                for (int r = 0; r < 4; ++r) {
                    int m = m0 + 64 * wr + 16 * mi + 4 * g + r;
                    Cf[(size_t)m * D_ + n] = acc[mi][nj][r];
                }
            }
        }
    } else {
        #pragma unroll
        for (int mi = 0; mi < 4; ++mi) {
            #pragma unroll
            for (int nj = 0; nj < 4; ++nj) {
                int n = n0 + 64 * wc + 16 * nj + ln;
                int which = n >> 10;
                int h  = (n >> 6) & (H_ - 1);
                int dh = n & (DH_ - 1);
                #pragma unroll
                for (int r = 0; r < 4; ++r) {
                    int m = m0 + 64 * wr + 16 * mi + 4 * g + r;
                    int b = m >> 11, ll = m & (L_ - 1);
                    ushort_t val = f2bf(acc[mi][nj][r]);
                    if (which == 2) {   // V: transposed scatter [bh][d][L]
                        Vo[((size_t)(b * H_ + h) * DH_ + dh) * L_ + ll] = val;
                    } else {
                        ushort_t* base = (which == 0) ? Qo : Ko;
                        base[((size_t)(b * H_ + h) * L_ + ll) * DH_ + dh] = val;
                    }
                }
            }
        }
    }
}

// ---------------------------------------------------------------------------
// RoPE bf16 -> bf16. Q pre-scaled by (1/8)*log2(e) so softmax can use 2^x.
// ---------------------------------------------------------------------------
#define QSCALE (0.125f * 1.44269504088896340736f)
__global__ __launch_bounds__(256)
void rope_bf16(const ushort_t* __restrict__ q, const ushort_t* __restrict__ k,
               ushort_t* __restrict__ qo, ushort_t* __restrict__ ko)
{
    int gid = blockIdx.x * 256 + threadIdx.x;       // B*H*L*8 threads
    int j4  = (gid & 7) * 4;
    int l   = (gid >> 3) & (L_ - 1);
    int bh  = gid >> 14;
    size_t base = ((size_t)bh * L_ + l) * DH_;

    ushort_t a1[4], a2[4], b1[4], b2[4], o1[4], o2[4], p1[4], p2[4];
    *(ushort4*)a1 = *(const ushort4*)(q + base + j4);
    *(ushort4*)a2 = *(const ushort4*)(q + base + j4 + 32);
    *(ushort4*)b1 = *(const ushort4*)(k + base + j4);
    *(ushort4*)b2 = *(const ushort4*)(k + base + j4 + 32);
    #pragma unroll
    for (int jj = 0; jj < 4; ++jj) {
        int j = j4 + jj;
        float inv = powf(10000.0f, -(float)j * (1.0f / 32.0f));
        float s, c;
        sincosf((float)l * inv, &s, &c);
        float q1 = bf2f(a1[jj]), q2 = bf2f(a2[jj]);
        o1[jj] = f2bf((q1 * c - q2 * s) * QSCALE);
        o2[jj] = f2bf((q2 * c + q1 * s) * QSCALE);
        float k1 = bf2f(b1[jj]), k2 = bf2f(b2[jj]);
        p1[jj] = f2bf(k1 * c - k2 * s);
        p2[jj] = f2bf(k2 * c + k1 * s);
    }
    *(ushort4*)(qo + base + j4)      = *(ushort4*)o1;
    *(ushort4*)(qo + base + j4 + 32) = *(ushort4*)o2;
    *(ushort4*)(ko + base + j4)      = *(ushort4*)p1;
    *(ushort4*)(ko + base + j4 + 32) = *(ushort4*)p2;
}

// ---------------------------------------------------------------------------
// Flash attention v6: NO K/V LDS staging, NO barriers. K+V per head = 512KB,
// L2-resident and shared by the 16 q-blocks per bh (Common-mistake #7 /
// m169: staging L2-fit data is pure overhead). Fragments load straight from
// global; K frags prefetched one tile ahead (2-deep named rotation), V frags
// issued at tile top and land under QK^T+softmax. Waves fully independent.
// P path (wave-private LDS, in-order DS) and all numerics unchanged from R7.
// Layouts: A: lane holds A[ln][32kk+8g+j]; B: lane holds Bt[ln][32kk+8g+j];
//          D: lane reg r -> D[4g+r][ln]   (g=lane>>4, ln=lane&15)
// ---------------------------------------------------------------------------
__global__ __launch_bounds__(256)
void attn_mfma(const ushort_t* __restrict__ qb, const ushort_t* __restrict__ kb,
               const ushort_t* __restrict__ vt, ushort_t* __restrict__ ao)
{
    __shared__ ushort_t Ps[4][32 * 64];     // per-wave P [32 q][64 key], swizzled

    const int t    = threadIdx.x;
    const int lane = t & 63, wv = t >> 6;
    const int g    = lane >> 4, ln = lane & 15;
    const int bh   = blockIdx.x;
    const int q0   = blockIdx.y * 128 + wv * 32;

    // Q fragments: half h covers rows q0+16h+ln
    const ushort_t* qpA = qb + ((size_t)bh * L_ + q0 + ln) * DH_;
    bf16x8 qf[2][2];
    qf[0][0] = *(const bf16x8*)(qpA + 8 * g);
    qf[0][1] = *(const bf16x8*)(qpA + 32 + 8 * g);
    qf[1][0] = *(const bf16x8*)(qpA + 16 * DH_ + 8 * g);
    qf[1][1] = *(const bf16x8*)(qpA + 16 * DH_ + 32 + 8 * g);

    // per-lane fragment base pointers (row varies with n; chunk with kk)
    const ushort_t* kp = kb + (size_t)bh * L_ * DH_ + (size_t)ln * DH_ + 8 * g;
    const ushort_t* vp = vt + (size_t)bh * DH_ * L_ + (size_t)ln * L_ + 8 * g;

    char* Pw = (char*)&Ps[wv][0];           // half h at byte offset 2048*h
    const int swz = (ln & 7) << 4;

    f32x4 O[2][4];
    #pragma unroll
    for (int h = 0; h < 2; ++h)
        #pragma unroll
        for (int n = 0; n < 4; ++n) O[h][n] = f32x4{0.f, 0.f, 0.f, 0.f};
    float m_q[2] = {-INFINITY, -INFINITY}, l_q[2] = {0.f, 0.f};

    // K fragment loader: kf[kk*4+n] = K[kt*64 + 16n + ln][32kk + 8g .. +8)
    auto loadK = [&](int kt, bf16x8* kf) {
        #pragma unroll
        for (int kk = 0; kk < 2; ++kk)
            #pragma unroll
            for (int n = 0; n < 4; ++n)
                kf[kk * 4 + n] =
                    *(const bf16x8*)(kp + (size_t)(kt * 64 + 16 * n) * DH_ + 32 * kk);
    };
    // V fragment loader: vf[kk*4+n] = Vt[16n + ln][kt*64 + 32kk + 8g .. +8)
    auto loadV = [&](int kt, bf16x8* vf) {
        #pragma unroll
        for (int kk = 0; kk < 2; ++kk)
            #pragma unroll
            for (int n = 0; n < 4; ++n)
                vf[kk * 4 + n] =
                    *(const bf16x8*)(vp + (size_t)(16 * n) * L_ + kt * 64 + 32 * kk);
    };

    auto process = [&](const bf16x8* kf, int kt) {
        // V frags for this tile: issue now, consumed after softmax
        bf16x8 vf[8];
        loadV(kt, vf);

        // ---- swapped QK^T: S[h][n][r] = S^T[key=16n+4g+r][q=16h+ln] ----
        f32x4 S[2][4];
        #pragma unroll
        for (int h = 0; h < 2; ++h)
            #pragma unroll
            for (int n = 0; n < 4; ++n) S[h][n] = f32x4{0.f, 0.f, 0.f, 0.f};
        __builtin_amdgcn_s_setprio(1);
        #pragma unroll
        for (int kk = 0; kk < 2; ++kk) {
            #pragma unroll
            for (int n = 0; n < 4; ++n) S[0][n] = MFMA16(kf[kk*4+n], qf[0][kk], S[0][n]);
            #pragma unroll
            for (int n = 0; n < 4; ++n) S[1][n] = MFMA16(kf[kk*4+n], qf[1][kk], S[1][n]);
        }
        __builtin_amdgcn_s_setprio(0);

        // ---- softmax per half (q = 16h + ln) ----
        #pragma unroll
        for (int h = 0; h < 2; ++h) {
            float pmax;
            {
                float a0 = fmaxf(fmaxf(S[h][0][0], S[h][0][1]), fmaxf(S[h][0][2], S[h][0][3]));
                float a1 = fmaxf(fmaxf(S[h][1][0], S[h][1][1]), fmaxf(S[h][1][2], S[h][1][3]));
                float a2 = fmaxf(fmaxf(S[h][2][0], S[h][2][1]), fmaxf(S[h][2][2], S[h][2][3]));
                float a3 = fmaxf(fmaxf(S[h][3][0], S[h][3][1]), fmaxf(S[h][3][2], S[h][3][3]));
                pmax = fmaxf(fmaxf(a0, a1), fmaxf(a2, a3));
            }
            pmax = fmaxf(pmax, __shfl_xor(pmax, 16));
            pmax = fmaxf(pmax, __shfl_xor(pmax, 32));

            if (!__all(pmax - m_q[h] <= 8.0f)) {   // defer-max (T13)
                float mnew = fmaxf(m_q[h], pmax);
                float al   = exp2_(m_q[h] - mnew);
                m_q[h] = mnew;
                l_q[h] *= al;
                #pragma unroll
                for (int r = 0; r < 4; ++r) {
                    float alr = bperm_f((4 * g + r) * 4, al);
                    #pragma unroll
                    for (int n = 0; n < 4; ++n) O[h][n][r] *= alr;
                }
            }

            float psum = 0.f;
            #pragma unroll
            for (int n = 0; n < 4; ++n) {
                float p0 = exp2_(S[h][n][0] - m_q[h]);
                float p1 = exp2_(S[h][n][1] - m_q[h]);
                float p2 = exp2_(S[h][n][2] - m_q[h]);
                float p3 = exp2_(S[h][n][3] - m_q[h]);
                psum += (p0 + p1) + (p2 + p3);
                uintx2 wq;
                wq[0] = cvtpk(p0, p1);
                wq[1] = cvtpk(p2, p3);
                *(uintx2*)(Pw + 2048 * h + 128 * ln + ((32 * n + 8 * g) ^ swz)) = wq;
            }
            psum += __shfl_xor(psum, 16);
            psum += __shfl_xor(psum, 32);
            l_q[h] += psum;
        }

        // ---- PV (P wave-private; same-wave DS in-order) ----
        #pragma unroll
        for (int kk = 0; kk < 2; ++kk) {
            bf16x8 pa0 = *(const bf16x8*)(Pw + 128 * ln + ((64 * kk + 16 * g) ^ swz));
            bf16x8 pa1 = *(const bf16x8*)(Pw + 2048 + 128 * ln + ((64 * kk + 16 * g) ^ swz));
            __builtin_amdgcn_s_setprio(1);
            #pragma unroll
            for (int n = 0; n < 4; ++n) O[0][n] = MFMA16(pa0, vf[kk*4+n], O[0][n]);
            #pragma unroll
            for (int n = 0; n < 4; ++n) O[1][n] = MFMA16(pa1, vf[kk*4+n], O[1][n]);
            __builtin_amdgcn_s_setprio(0);
        }
    };

    constexpr int NT = L_ / 64;   // 32 tiles
    bf16x8 kfA[8], kfB[8];
    loadK(0, kfA);
    for (int kt = 0; kt < NT; kt += 2) {
        loadK(kt + 1, kfB);           // prefetch next tile's K frags
        process(kfA, kt);
        if (kt + 2 < NT) loadK(kt + 2, kfA);
        process(kfB, kt + 1);
    }

    // epilogue: pull l for q=16h+4g+r, normalize, write bf16 ao [B][L][D]
    const int b = bh >> 4, hh = bh & 15;
    #pragma unroll
    for (int h = 0; h < 2; ++h) {
        #pragma unroll
        for (int r = 0; r < 4; ++r) {
            float lb  = bperm_f((4 * g + r) * 4, l_q[h]);
            float inv = 1.0f / lb;
            int ql = q0 + 16 * h + 4 * g + r;
            ushort_t* dst = ao + ((size_t)(b * L_ + ql)) * D_ + hh * 64;
            #pragma unroll
            for (int n = 0; n < 4; ++n)
                dst[16 * n + ln] = f2bf(O[h][n][r] * inv);
        }
    }
}

// ---------------------------------------------------------------------------
extern "C" void kernel_launch(void* const* d_in, const int* in_sizes, int n_in,
                              void* d_out, int out_size, void* d_ws, size_t ws_size,
                              hipStream_t stream)
{
    const float* x    = (const float*)d_in[0];
    const float* Wqkv = (const float*)d_in[1];
    const float* Wo   = (const float*)d_in[2];
    float* out = (float*)d_out;

    char* ws = (char*)d_ws;                               // 64 MB layout:
    ushort_t* xb  = (ushort_t*)(ws);                      // [0,8M)   x bf16; later ao
    ushort_t* wqt = (ushort_t*)(ws + ((size_t) 8 << 20)); // [8,14M)  Wqkv^T bf16
    ushort_t* wot = (ushort_t*)(ws + ((size_t)14 << 20)); // [14,16M) Wo^T bf16
    ushort_t* qB  = (ushort_t*)(ws + ((size_t)16 << 20)); // [16,24M) q pre-rope
    ushort_t* kB  = (ushort_t*)(ws + ((size_t)24 << 20)); // [24,32M) k pre-rope
    ushort_t* vt  = (ushort_t*)(ws + ((size_t)32 << 20)); // [32,40M) v^T (from GEMM)
    ushort_t* qR  = (ushort_t*)(ws + ((size_t)40 << 20)); // [40,48M) q rope'd
    ushort_t* kR  = (ushort_t*)(ws + ((size_t)48 << 20)); // [48,56M) k rope'd
    ushort_t* ao  = xb;                                   // alias (xb dead post-gemm)

    convert_x<<<(M_ * D_) / (8 * 256), 256, 0, stream>>>(x, xb);
    transpose_w<N1_><<<dim3(N1_ / 64, 16), 256, 0, stream>>>(Wqkv, wqt);
    transpose_w<D_ ><<<dim3(D_  / 64, 16), 256, 0, stream>>>(Wo, wot);

    bgemm<1><<<dim3(N1_ / 128, M_ / 128), 256, 0, stream>>>(xb, wqt, nullptr, qB, kB, vt);
    rope_bf16<<<(B_ * H_ * L_ * 8) / 256, 256, 0, stream>>>(qB, kB, qR, kR);
    attn_mfma<<<dim3(B_ * H_, L_ / 128), 256, 0, stream>>>(qR, kR, vt, ao);
    bgemm<0><<<dim3(D_ / 128, M_ / 128), 256, 0, stream>>>(ao, wot, out, nullptr, nullptr, nullptr);
}

// Round 9
// 148.701 us; speedup vs baseline: 1.3883x; 1.3883x over previous
//
#include <hip/hip_runtime.h>
#include <hip/hip_bf16.h>

#define B_  2
#define L_  2048
#define D_  1024
#define H_  16
#define DH_ 64
#define M_  (B_*L_)     // 4096
#define N1_ (3*D_)      // 3072

#define QSCALE (0.125f * 1.44269504088896340736f)   // 1/sqrt(64) * log2(e)

typedef __bf16 bf16x8 __attribute__((ext_vector_type(8)));
typedef float  f32x4  __attribute__((ext_vector_type(4)));
typedef unsigned short ushort_t;
typedef unsigned short ushort8_t __attribute__((ext_vector_type(8)));
typedef unsigned int   uintx2    __attribute__((ext_vector_type(2)));

#define MFMA16(a,b,c) __builtin_amdgcn_mfma_f32_16x16x32_bf16((a),(b),(c),0,0,0)

__device__ __forceinline__ float4 ld4(const float* p) { return *(const float4*)p; }

__device__ __forceinline__ ushort_t f2bf(float f) {
    union { float f; unsigned int u; } v; v.f = f;
    unsigned int r = (v.u + 0x7FFFu + ((v.u >> 16) & 1u)) >> 16;
    return (ushort_t)r;
}
__device__ __forceinline__ float bf2f(ushort_t u) {
    union { unsigned int u; float f; } v; v.u = ((unsigned int)u) << 16;
    return v.f;
}
// v_exp_f32 computes 2^x
__device__ __forceinline__ float exp2_(float x) {
    float r; asm("v_exp_f32 %0, %1" : "=v"(r) : "v"(x)); return r;
}
// packed f32 pair -> bf16 pair (lo = a, hi = b)
__device__ __forceinline__ unsigned cvtpk(float a, float b) {
    unsigned r; asm("v_cvt_pk_bf16_f32 %0, %1, %2" : "=v"(r) : "v"(a), "v"(b)); return r;
}
// pull float from lane (byte_addr = src_lane*4)
__device__ __forceinline__ float bperm_f(int byte_addr, float v) {
    union { float f; int i; } u; u.f = v;
    u.i = __builtin_amdgcn_ds_bpermute(byte_addr, u.i);
    return u.f;
}
// async global->LDS, 16B per lane; LDS dest = wave-uniform base + lane*16
__device__ __forceinline__ void gload16(const ushort_t* g, ushort_t* l) {
    __builtin_amdgcn_global_load_lds(
        (const __attribute__((address_space(1))) unsigned int*)g,
        (__attribute__((address_space(3))) unsigned int*)l, 16, 0, 0);
}

// ---------------------------------------------------------------------------
// x fp32 -> bf16, elementwise, 8/thread
// ---------------------------------------------------------------------------
__global__ __launch_bounds__(256)
void convert_x(const float* __restrict__ in, ushort_t* __restrict__ out)
{
    int i = (blockIdx.x * 256 + threadIdx.x) * 8;
    float4 a = ld4(in + i), b = ld4(in + i + 4);
    ushort8_t o;
    o[0] = f2bf(a.x); o[1] = f2bf(a.y); o[2] = f2bf(a.z); o[3] = f2bf(a.w);
    o[4] = f2bf(b.x); o[5] = f2bf(b.y); o[6] = f2bf(b.z); o[7] = f2bf(b.w);
    *(ushort8_t*)(out + i) = o;
}

// ---------------------------------------------------------------------------
// W fp32 [1024][N] -> bf16 W^T [N][1024], 64x64 LDS tiles
// ---------------------------------------------------------------------------
template<int N>
__global__ __launch_bounds__(256)
void transpose_w(const float* __restrict__ in, ushort_t* __restrict__ out)
{
    __shared__ float vs[64][65];
    const int nt = blockIdx.x, kt = blockIdx.y, t = threadIdx.x;
    #pragma unroll
    for (int i = 0; i < 4; ++i) {
        int idx = t + 256 * i;
        int row = idx >> 4, c4 = idx & 15;
        float4 x4 = ld4(in + (size_t)(kt * 64 + row) * N + nt * 64 + c4 * 4);
        vs[row][c4*4+0] = x4.x; vs[row][c4*4+1] = x4.y;
        vs[row][c4*4+2] = x4.z; vs[row][c4*4+3] = x4.w;
    }
    __syncthreads();
    #pragma unroll
    for (int i = 0; i < 16; ++i) {
        int idx = t + 256 * i;
        int nc = idx >> 6, kc = idx & 63;
        out[(size_t)(nt * 64 + nc) * 1024 + kt * 64 + kc] = f2bf(vs[kc][nc]);
    }
}

// ---------------------------------------------------------------------------
// bf16 MFMA GEMM, m97 structure. EPI 0: fp32 C.
// EPI 1: QKV scatter with FUSED ROPE on Q,K (acc pairs nj<->nj+2 are the
// (dh, dh+32) rotation partners; rotate in fp32 before bf16 rounding) and
// V written TRANSPOSED (vt [bh][64 d][L]).
// ---------------------------------------------------------------------------
template<int EPI>
__global__ __launch_bounds__(256)
void bgemm(const ushort_t* __restrict__ A, const ushort_t* __restrict__ Bt,
           float* __restrict__ Cf,
           ushort_t* __restrict__ Qo, ushort_t* __restrict__ Ko, ushort_t* __restrict__ Vo)
{
    constexpr int K = 1024;
    __shared__ ushort_t As[128 * 64];
    __shared__ ushort_t Bs[128 * 64];
    const int t  = threadIdx.x;
    const int l  = t & 63, w = t >> 6;
    const int g  = l >> 4, ln = l & 15;
    const int wr = w >> 1, wc = w & 1;
    const int m0 = blockIdx.y * 128, n0 = blockIdx.x * 128;

    const int srow = w * 8 + (l >> 3);
    const int sch  = (l & 7) ^ (l >> 3);
    const ushort_t* Ag = A  + ((size_t)(m0 + srow)) * K + sch * 8;
    const ushort_t* Bg = Bt + ((size_t)(n0 + srow)) * K + sch * 8;

    f32x4 acc[4][4];
    #pragma unroll
    for (int mi = 0; mi < 4; ++mi)
        #pragma unroll
        for (int nj = 0; nj < 4; ++nj) acc[mi][nj] = f32x4{0.f, 0.f, 0.f, 0.f};

    for (int kt = 0; kt < K / 64; ++kt) {
        #pragma unroll
        for (int i = 0; i < 4; ++i)
            gload16(Ag + (size_t)i * 32 * K + kt * 64, &As[i * 2048 + w * 512]);
        #pragma unroll
        for (int i = 0; i < 4; ++i)
            gload16(Bg + (size_t)i * 32 * K + kt * 64, &Bs[i * 2048 + w * 512]);
        __syncthreads();

        #pragma unroll
        for (int kk = 0; kk < 2; ++kk) {
            bf16x8 af[4], bfv[4];
            #pragma unroll
            for (int mi = 0; mi < 4; ++mi) {
                int row  = 64 * wr + 16 * mi + ln;
                int phys = (4 * kk + g) ^ (ln & 7);
                af[mi] = *(const bf16x8*)&As[row * 64 + phys * 8];
            }
            #pragma unroll
            for (int nj = 0; nj < 4; ++nj) {
                int row  = 64 * wc + 16 * nj + ln;
                int phys = (4 * kk + g) ^ (ln & 7);
                bfv[nj] = *(const bf16x8*)&Bs[row * 64 + phys * 8];
            }
            #pragma unroll
            for (int mi = 0; mi < 4; ++mi)
                #pragma unroll
                for (int nj = 0; nj < 4; ++nj)
                    acc[mi][nj] = MFMA16(af[mi], bfv[nj], acc[mi][nj]);
        }
        __syncthreads();
    }

    if (EPI == 0) {
        #pragma unroll
        for (int mi = 0; mi < 4; ++mi) {
            #pragma unroll
            for (int nj = 0; nj < 4; ++nj) {
                int n = n0 + 64 * wc + 16 * nj + ln;
                #pragma unroll
                for (int r = 0; r < 4; ++r) {
                    int m = m0 + 64 * wr + 16 * mi + 4 * g + r;
                    Cf[(size_t)m * D_ + n] = acc[mi][nj][r];
                }
            }
        }
    } else {
        // all four nj share one 64-column block -> same (which, head)
        const int nb    = n0 + 64 * wc;
        const int which = nb >> 10;
        const int h     = (nb >> 6) & (H_ - 1);
        if (which == 2) {           // V: transposed scatter [bh][d][L]
            #pragma unroll
            for (int mi = 0; mi < 4; ++mi)
                #pragma unroll
                for (int nj = 0; nj < 4; ++nj) {
                    int dh = 16 * nj + ln;
                    #pragma unroll
                    for (int r = 0; r < 4; ++r) {
                        int m = m0 + 64 * wr + 16 * mi + 4 * g + r;
                        int b = m >> 11, ll = m & (L_ - 1);
                        Vo[((size_t)(b * H_ + h) * DH_ + dh) * L_ + ll] = f2bf(acc[mi][nj][r]);
                    }
                }
        } else {                    // Q or K: fused RoPE (pairs nj & nj+2)
            ushort_t* base = (which == 0) ? Qo : Ko;
            const float scale = (which == 0) ? QSCALE : 1.0f;
            const float inv0 = powf(10000.0f, -(float)ln * (1.0f / 32.0f));
            const float inv1 = powf(10000.0f, -(float)(16 + ln) * (1.0f / 32.0f));
            #pragma unroll
            for (int mi = 0; mi < 4; ++mi) {
                #pragma unroll
                for (int r = 0; r < 4; ++r) {
                    int m = m0 + 64 * wr + 16 * mi + 4 * g + r;
                    int b = m >> 11, ll = m & (L_ - 1);
                    float s0, c0, s1, c1;
                    sincosf((float)ll * inv0, &s0, &c0);
                    sincosf((float)ll * inv1, &s1, &c1);
                    size_t rb = ((size_t)(b * H_ + h) * L_ + ll) * DH_;
                    float a1 = acc[mi][0][r], a2 = acc[mi][2][r];   // dh=ln, ln+32
                    base[rb + ln]      = f2bf((a1 * c0 - a2 * s0) * scale);
                    base[rb + ln + 32] = f2bf((a2 * c0 + a1 * s0) * scale);
                    float b1 = acc[mi][1][r], b2 = acc[mi][3][r];   // dh=16+ln, 48+ln
                    base[rb + 16 + ln]      = f2bf((b1 * c1 - b2 * s1) * scale);
                    base[rb + 16 + ln + 32] = f2bf((b2 * c1 + b1 * s1) * scale);
                }
            }
        }
    }
}

// ---------------------------------------------------------------------------
// Flash attention v7: R7 structure (shared LDS staging, counted vmcnt,
// raw barriers + compiler fences, swapped QK^T, defer-max, packed P) with
// KVBLK=128: two 64-key sub-tiles per barrier pair -> half the barriers.
// K LDS rows 128B (swizzle chunk^=row&7 over 8 chunks); V LDS rows 256B
// (swizzle chunk^=row&7 over 16 chunks, both-sides per rule 21).
// Layouts: A: lane holds A[ln][32kk+8g+j]; B: lane holds Bt[ln][32kk+8g+j];
//          D: lane reg r -> D[4g+r][ln]   (g=lane>>4, ln=lane&15)
// ---------------------------------------------------------------------------
__global__ __launch_bounds__(256)
void attn_mfma(const ushort_t* __restrict__ qb, const ushort_t* __restrict__ kb,
               const ushort_t* __restrict__ vt, ushort_t* __restrict__ ao)
{
    __shared__ ushort_t Ks[2][128 * 64];    // [key][d], 128B rows, swizzled
    __shared__ ushort_t Vs[2][64 * 128];    // [d][key], 256B rows, swizzled
    __shared__ ushort_t Ps[4][32 * 64];     // per-wave P [32 q][64 key], swizzled

    const int t    = threadIdx.x;
    const int lane = t & 63, wv = t >> 6;
    const int g    = lane >> 4, ln = lane & 15;
    const int bh   = blockIdx.x;
    const int q0   = blockIdx.y * 128 + wv * 32;

    // Q fragments: half h covers rows q0+16h+ln
    const ushort_t* qpA = qb + ((size_t)bh * L_ + q0 + ln) * DH_;
    bf16x8 qf[2][2];
    qf[0][0] = *(const bf16x8*)(qpA + 8 * g);
    qf[0][1] = *(const bf16x8*)(qpA + 32 + 8 * g);
    qf[1][0] = *(const bf16x8*)(qpA + 16 * DH_ + 8 * g);
    qf[1][1] = *(const bf16x8*)(qpA + 16 * DH_ + 32 + 8 * g);

    const ushort_t* kp = kb + (size_t)bh * L_ * DH_;
    const ushort_t* vp = vt + (size_t)bh * DH_ * L_;

    // K staging: issue i covers tile rows 32wv+8i..+8 (row&7 = lane>>3)
    const int krow8 = lane >> 3;
    const int ksch  = (lane & 7) ^ krow8;
    // V staging: issue i covers d-rows 16wv+4i..+4 (row&7 = (4i+lane>>4)&7)
    const int vrow4 = lane >> 4;

    char* Pw = (char*)&Ps[wv][0];           // half h at byte offset 2048*h
    const int swz = (ln & 7) << 4;

    f32x4 O[2][4];
    #pragma unroll
    for (int h = 0; h < 2; ++h)
        #pragma unroll
        for (int n = 0; n < 4; ++n) O[h][n] = f32x4{0.f, 0.f, 0.f, 0.f};
    float m_q[2] = {-INFINITY, -INFINITY}, l_q[2] = {0.f, 0.f};

    auto stage = [&](int tt, int buf) {
        #pragma unroll
        for (int i = 0; i < 4; ++i) {
            int row = 32 * wv + 8 * i + krow8;
            gload16(kp + ((size_t)(tt * 128 + row)) * 64 + ksch * 8,
                    &Ks[buf][(32 * wv + 8 * i) * 64]);
        }
        #pragma unroll
        for (int i = 0; i < 4; ++i) {
            int row  = 16 * wv + 4 * i + vrow4;
            int vsch = (lane & 15) ^ ((4 * i + vrow4) & 7);
            gload16(vp + ((size_t)row) * L_ + tt * 128 + vsch * 8,
                    &Vs[buf][(16 * wv + 4 * i) * 128]);
        }
    };

    auto process = [&](const ushort_t* Kc, const ushort_t* Vc, int sub) {
        // ---- swapped QK^T: S[h][n][r] = S^T[key=64sub+16n+4g+r][q=16h+ln] ----
        f32x4 S[2][4];
        #pragma unroll
        for (int h = 0; h < 2; ++h)
            #pragma unroll
            for (int n = 0; n < 4; ++n) S[h][n] = f32x4{0.f, 0.f, 0.f, 0.f};
        #pragma unroll
        for (int kk = 0; kk < 2; ++kk) {
            bf16x8 kfv[4];
            #pragma unroll
            for (int n = 0; n < 4; ++n) {
                int row  = 64 * sub + 16 * n + ln;      // row&7 == ln&7
                int phys = (4 * kk + g) ^ (ln & 7);
                kfv[n] = *(const bf16x8*)&Kc[row * 64 + phys * 8];
            }
            __builtin_amdgcn_s_setprio(1);
            #pragma unroll
            for (int n = 0; n < 4; ++n) S[0][n] = MFMA16(kfv[n], qf[0][kk], S[0][n]);
            #pragma unroll
            for (int n = 0; n < 4; ++n) S[1][n] = MFMA16(kfv[n], qf[1][kk], S[1][n]);
            __builtin_amdgcn_s_setprio(0);
        }

        // ---- softmax per half (q = 16h + ln) ----
        #pragma unroll
        for (int h = 0; h < 2; ++h) {
            float pmax;
            {
                float a0 = fmaxf(fmaxf(S[h][0][0], S[h][0][1]), fmaxf(S[h][0][2], S[h][0][3]));
                float a1 = fmaxf(fmaxf(S[h][1][0], S[h][1][1]), fmaxf(S[h][1][2], S[h][1][3]));
                float a2 = fmaxf(fmaxf(S[h][2][0], S[h][2][1]), fmaxf(S[h][2][2], S[h][2][3]));
                float a3 = fmaxf(fmaxf(S[h][3][0], S[h][3][1]), fmaxf(S[h][3][2], S[h][3][3]));
                pmax = fmaxf(fmaxf(a0, a1), fmaxf(a2, a3));
            }
            pmax = fmaxf(pmax, __shfl_xor(pmax, 16));
            pmax = fmaxf(pmax, __shfl_xor(pmax, 32));

            if (!__all(pmax - m_q[h] <= 8.0f)) {   // defer-max (T13)
                float mnew = fmaxf(m_q[h], pmax);
                float al   = exp2_(m_q[h] - mnew);
                m_q[h] = mnew;
                l_q[h] *= al;
                #pragma unroll
                for (int r = 0; r < 4; ++r) {
                    float alr = bperm_f((4 * g + r) * 4, al);
                    #pragma unroll
                    for (int n = 0; n < 4; ++n) O[h][n][r] *= alr;
                }
            }

            float psum = 0.f;
            #pragma unroll
            for (int n = 0; n < 4; ++n) {
                float p0 = exp2_(S[h][n][0] - m_q[h]);
                float p1 = exp2_(S[h][n][1] - m_q[h]);
                float p2 = exp2_(S[h][n][2] - m_q[h]);
                float p3 = exp2_(S[h][n][3] - m_q[h]);
                psum += (p0 + p1) + (p2 + p3);
                uintx2 wq;
                wq[0] = cvtpk(p0, p1);
                wq[1] = cvtpk(p2, p3);
                *(uintx2*)(Pw + 2048 * h + 128 * ln + ((32 * n + 8 * g) ^ swz)) = wq;
            }
            psum += __shfl_xor(psum, 16);
            psum += __shfl_xor(psum, 32);
            l_q[h] += psum;
        }

        // ---- PV (P wave-private; same-wave DS in-order; no barrier) ----
        #pragma unroll
        for (int kk = 0; kk < 2; ++kk) {
            bf16x8 vfv[4];
            #pragma unroll
            for (int n = 0; n < 4; ++n) {
                int row  = 16 * n + ln;                 // row&7 == ln&7
                int phys = 8 * sub + ((4 * kk + g) ^ (ln & 7));
                vfv[n] = *(const bf16x8*)&Vc[row * 128 + phys * 8];
            }
            bf16x8 pa0 = *(const bf16x8*)(Pw + 128 * ln + ((64 * kk + 16 * g) ^ swz));
            bf16x8 pa1 = *(const bf16x8*)(Pw + 2048 + 128 * ln + ((64 * kk + 16 * g) ^ swz));
            __builtin_amdgcn_s_setprio(1);
            #pragma unroll
            for (int n = 0; n < 4; ++n) O[0][n] = MFMA16(pa0, vfv[n], O[0][n]);
            #pragma unroll
            for (int n = 0; n < 4; ++n) O[1][n] = MFMA16(pa1, vfv[n], O[1][n]);
            __builtin_amdgcn_s_setprio(0);
        }
    };

    stage(0, 0);
    for (int tt = 0; tt < L_ / 128; ++tt) {
        const int cur = tt & 1, nxt = cur ^ 1;
        const int nk  = (tt < L_ / 128 - 1) ? tt + 1 : tt;  // clamp: redundant reload
        stage(nk, nxt);
        asm volatile("s_waitcnt vmcnt(8)" ::: "memory");  // my tile-tt loads landed
        __builtin_amdgcn_s_barrier();                      // landed for ALL waves
        asm volatile("" ::: "memory");   // fence: no LDS reads above the barrier
        process(&Ks[cur][0], &Vs[cur][0], 0);
        process(&Ks[cur][0], &Vs[cur][0], 1);
        __builtin_amdgcn_s_barrier();    // all waves done reading buf[cur]
        asm volatile("" ::: "memory");   // fence: next staging stays below
    }
    asm volatile("s_waitcnt vmcnt(0)" ::: "memory");  // drain redundant tail loads

    // epilogue: pull l for q=16h+4g+r, normalize, write bf16 ao [B][L][D]
    const int b = bh >> 4, hh = bh & 15;
    #pragma unroll
    for (int h = 0; h < 2; ++h) {
        #pragma unroll
        for (int r = 0; r < 4; ++r) {
            float lb  = bperm_f((4 * g + r) * 4, l_q[h]);
            float inv = 1.0f / lb;
            int ql = q0 + 16 * h + 4 * g + r;
            ushort_t* dst = ao + ((size_t)(b * L_ + ql)) * D_ + hh * 64;
            #pragma unroll
            for (int n = 0; n < 4; ++n)
                dst[16 * n + ln] = f2bf(O[h][n][r] * inv);
        }
    }
}

// ---------------------------------------------------------------------------
extern "C" void kernel_launch(void* const* d_in, const int* in_sizes, int n_in,
                              void* d_out, int out_size, void* d_ws, size_t ws_size,
                              hipStream_t stream)
{
    const float* x    = (const float*)d_in[0];
    const float* Wqkv = (const float*)d_in[1];
    const float* Wo   = (const float*)d_in[2];
    float* out = (float*)d_out;

    char* ws = (char*)d_ws;                               // 64 MB layout:
    ushort_t* xb  = (ushort_t*)(ws);                      // [0,8M)   x bf16; later ao
    ushort_t* wqt = (ushort_t*)(ws + ((size_t) 8 << 20)); // [8,14M)  Wqkv^T bf16
    ushort_t* wot = (ushort_t*)(ws + ((size_t)14 << 20)); // [14,16M) Wo^T bf16
    ushort_t* qR  = (ushort_t*)(ws + ((size_t)16 << 20)); // [16,24M) q rope'd (from GEMM)
    ushort_t* kR  = (ushort_t*)(ws + ((size_t)24 << 20)); // [24,32M) k rope'd (from GEMM)
    ushort_t* vt  = (ushort_t*)(ws + ((size_t)32 << 20)); // [32,40M) v^T (from GEMM)
    ushort_t* ao  = xb;                                   // alias (xb dead post-gemm)

    convert_x<<<(M_ * D_) / (8 * 256), 256, 0, stream>>>(x, xb);
    transpose_w<N1_><<<dim3(N1_ / 64, 16), 256, 0, stream>>>(Wqkv, wqt);
    transpose_w<D_ ><<<dim3(D_  / 64, 16), 256, 0, stream>>>(Wo, wot);

    bgemm<1><<<dim3(N1_ / 128, M_ / 128), 256, 0, stream>>>(xb, wqt, nullptr, qR, kR, vt);
    attn_mfma<<<dim3(B_ * H_, L_ / 128), 256, 0, stream>>>(qR, kR, vt, ao);
    bgemm<0><<<dim3(D_ / 128, M_ / 128), 256, 0, stream>>>(ao, wot, out, nullptr, nullptr, nullptr);
}

// Round 10
// 144.731 us; speedup vs baseline: 1.4264x; 1.0274x over previous
//
#include <hip/hip_runtime.h>
#include <hip/hip_bf16.h>

#define B_  2
#define L_  2048
#define D_  1024
#define H_  16
#define DH_ 64
#define M_  (B_*L_)     // 4096
#define N1_ (3*D_)      // 3072

#define QSCALE (0.125f * 1.44269504088896340736f)   // 1/sqrt(64) * log2(e)

typedef __bf16 bf16x8 __attribute__((ext_vector_type(8)));
typedef float  f32x4  __attribute__((ext_vector_type(4)));
typedef unsigned short ushort_t;
typedef unsigned short ushort8_t __attribute__((ext_vector_type(8)));
typedef unsigned int   uintx2    __attribute__((ext_vector_type(2)));

#define MFMA16(a,b,c) __builtin_amdgcn_mfma_f32_16x16x32_bf16((a),(b),(c),0,0,0)

__device__ __forceinline__ float4 ld4(const float* p) { return *(const float4*)p; }

__device__ __forceinline__ ushort_t f2bf(float f) {
    union { float f; unsigned int u; } v; v.f = f;
    unsigned int r = (v.u + 0x7FFFu + ((v.u >> 16) & 1u)) >> 16;
    return (ushort_t)r;
}
__device__ __forceinline__ float bf2f(ushort_t u) {
    union { unsigned int u; float f; } v; v.u = ((unsigned int)u) << 16;
    return v.f;
}
// v_exp_f32 computes 2^x
__device__ __forceinline__ float exp2_(float x) {
    float r; asm("v_exp_f32 %0, %1" : "=v"(r) : "v"(x)); return r;
}
// hardware trig: input in REVOLUTIONS, reduce with v_fract first (ISA §3)
__device__ __forceinline__ float fract_(float x) {
    float r; asm("v_fract_f32 %0, %1" : "=v"(r) : "v"(x)); return r;
}
__device__ __forceinline__ float sin_rev(float x) {
    float r; asm("v_sin_f32 %0, %1" : "=v"(r) : "v"(x)); return r;
}
__device__ __forceinline__ float cos_rev(float x) {
    float r; asm("v_cos_f32 %0, %1" : "=v"(r) : "v"(x)); return r;
}
// packed f32 pair -> bf16 pair (lo = a, hi = b)
__device__ __forceinline__ unsigned cvtpk(float a, float b) {
    unsigned r; asm("v_cvt_pk_bf16_f32 %0, %1, %2" : "=v"(r) : "v"(a), "v"(b)); return r;
}
// pull float from lane (byte_addr = src_lane*4)
__device__ __forceinline__ float bperm_f(int byte_addr, float v) {
    union { float f; int i; } u; u.f = v;
    u.i = __builtin_amdgcn_ds_bpermute(byte_addr, u.i);
    return u.f;
}
// async global->LDS, 16B per lane; LDS dest = wave-uniform base + lane*16
__device__ __forceinline__ void gload16(const ushort_t* g, ushort_t* l) {
    __builtin_amdgcn_global_load_lds(
        (const __attribute__((address_space(1))) unsigned int*)g,
        (__attribute__((address_space(3))) unsigned int*)l, 16, 0, 0);
}

// ---------------------------------------------------------------------------
// x fp32 -> bf16, elementwise, 8/thread
// ---------------------------------------------------------------------------
__global__ __launch_bounds__(256)
void convert_x(const float* __restrict__ in, ushort_t* __restrict__ out)
{
    int i = (blockIdx.x * 256 + threadIdx.x) * 8;
    float4 a = ld4(in + i), b = ld4(in + i + 4);
    ushort8_t o;
    o[0] = f2bf(a.x); o[1] = f2bf(a.y); o[2] = f2bf(a.z); o[3] = f2bf(a.w);
    o[4] = f2bf(b.x); o[5] = f2bf(b.y); o[6] = f2bf(b.z); o[7] = f2bf(b.w);
    *(ushort8_t*)(out + i) = o;
}

// ---------------------------------------------------------------------------
// W fp32 [1024][N] -> bf16 W^T [N][1024], 64x64 LDS tiles
// ---------------------------------------------------------------------------
template<int N>
__global__ __launch_bounds__(256)
void transpose_w(const float* __restrict__ in, ushort_t* __restrict__ out)
{
    __shared__ float vs[64][65];
    const int nt = blockIdx.x, kt = blockIdx.y, t = threadIdx.x;
    #pragma unroll
    for (int i = 0; i < 4; ++i) {
        int idx = t + 256 * i;
        int row = idx >> 4, c4 = idx & 15;
        float4 x4 = ld4(in + (size_t)(kt * 64 + row) * N + nt * 64 + c4 * 4);
        vs[row][c4*4+0] = x4.x; vs[row][c4*4+1] = x4.y;
        vs[row][c4*4+2] = x4.z; vs[row][c4*4+3] = x4.w;
    }
    __syncthreads();
    #pragma unroll
    for (int i = 0; i < 16; ++i) {
        int idx = t + 256 * i;
        int nc = idx >> 6, kc = idx & 63;
        out[(size_t)(nt * 64 + nc) * 1024 + kt * 64 + kc] = f2bf(vs[kc][nc]);
    }
}

// ---------------------------------------------------------------------------
// bf16 MFMA GEMM, m97 structure. EPI 0: fp32 C.
// EPI 1: QKV scatter with FUSED ROPE on Q,K (acc pairs nj<->nj+2 are the
// (dh, dh+32) rotation partners; rotate in fp32 before bf16 rounding) and
// V written TRANSPOSED (vt [bh][64 d][L]).
// R10: epilogue trig = HW v_sin/v_cos in revolutions (libm sincosf/powf
// was ~3-6k cyc/thread tacked onto a 16-step K-loop).
// ---------------------------------------------------------------------------
template<int EPI>
__global__ __launch_bounds__(256)
void bgemm(const ushort_t* __restrict__ A, const ushort_t* __restrict__ Bt,
           float* __restrict__ Cf,
           ushort_t* __restrict__ Qo, ushort_t* __restrict__ Ko, ushort_t* __restrict__ Vo)
{
    constexpr int K = 1024;
    __shared__ ushort_t As[128 * 64];
    __shared__ ushort_t Bs[128 * 64];
    const int t  = threadIdx.x;
    const int l  = t & 63, w = t >> 6;
    const int g  = l >> 4, ln = l & 15;
    const int wr = w >> 1, wc = w & 1;
    const int m0 = blockIdx.y * 128, n0 = blockIdx.x * 128;

    const int srow = w * 8 + (l >> 3);
    const int sch  = (l & 7) ^ (l >> 3);
    const ushort_t* Ag = A  + ((size_t)(m0 + srow)) * K + sch * 8;
    const ushort_t* Bg = Bt + ((size_t)(n0 + srow)) * K + sch * 8;

    f32x4 acc[4][4];
    #pragma unroll
    for (int mi = 0; mi < 4; ++mi)
        #pragma unroll
        for (int nj = 0; nj < 4; ++nj) acc[mi][nj] = f32x4{0.f, 0.f, 0.f, 0.f};

    for (int kt = 0; kt < K / 64; ++kt) {
        #pragma unroll
        for (int i = 0; i < 4; ++i)
            gload16(Ag + (size_t)i * 32 * K + kt * 64, &As[i * 2048 + w * 512]);
        #pragma unroll
        for (int i = 0; i < 4; ++i)
            gload16(Bg + (size_t)i * 32 * K + kt * 64, &Bs[i * 2048 + w * 512]);
        __syncthreads();

        #pragma unroll
        for (int kk = 0; kk < 2; ++kk) {
            bf16x8 af[4], bfv[4];
            #pragma unroll
            for (int mi = 0; mi < 4; ++mi) {
                int row  = 64 * wr + 16 * mi + ln;
                int phys = (4 * kk + g) ^ (ln & 7);
                af[mi] = *(const bf16x8*)&As[row * 64 + phys * 8];
            }
            #pragma unroll
            for (int nj = 0; nj < 4; ++nj) {
                int row  = 64 * wc + 16 * nj + ln;
                int phys = (4 * kk + g) ^ (ln & 7);
                bfv[nj] = *(const bf16x8*)&Bs[row * 64 + phys * 8];
            }
            #pragma unroll
            for (int mi = 0; mi < 4; ++mi)
                #pragma unroll
                for (int nj = 0; nj < 4; ++nj)
                    acc[mi][nj] = MFMA16(af[mi], bfv[nj], acc[mi][nj]);
        }
        __syncthreads();
    }

    if (EPI == 0) {
        #pragma unroll
        for (int mi = 0; mi < 4; ++mi) {
            #pragma unroll
            for (int nj = 0; nj < 4; ++nj) {
                int n = n0 + 64 * wc + 16 * nj + ln;
                #pragma unroll
                for (int r = 0; r < 4; ++r) {
                    int m = m0 + 64 * wr + 16 * mi + 4 * g + r;
                    Cf[(size_t)m * D_ + n] = acc[mi][nj][r];
                }
            }
        }
    } else {
        // all four nj share one 64-column block -> same (which, head)
        const int nb    = n0 + 64 * wc;
        const int which = nb >> 10;
        const int h     = (nb >> 6) & (H_ - 1);
        if (which == 2) {           // V: transposed scatter [bh][d][L]
            #pragma unroll
            for (int mi = 0; mi < 4; ++mi)
                #pragma unroll
                for (int nj = 0; nj < 4; ++nj) {
                    int dh = 16 * nj + ln;
                    #pragma unroll
                    for (int r = 0; r < 4; ++r) {
                        int m = m0 + 64 * wr + 16 * mi + 4 * g + r;
                        int b = m >> 11, ll = m & (L_ - 1);
                        Vo[((size_t)(b * H_ + h) * DH_ + dh) * L_ + ll] = f2bf(acc[mi][nj][r]);
                    }
                }
        } else {                    // Q or K: fused RoPE (pairs nj & nj+2)
            ushort_t* base = (which == 0) ? Qo : Ko;
            const float scale = (which == 0) ? QSCALE : 1.0f;
            // inv = 10000^(-j/32) via 2^(-j*log2(1e4)/32); pre-divide by 2pi
            // so angles are in revolutions for v_sin/v_cos.
            const float invr0 = exp2_(-(float)ln        * 0.41524101186f) * 0.15915494310f;
            const float invr1 = exp2_(-(float)(16 + ln) * 0.41524101186f) * 0.15915494310f;
            #pragma unroll
            for (int mi = 0; mi < 4; ++mi) {
                #pragma unroll
                for (int r = 0; r < 4; ++r) {
                    int m = m0 + 64 * wr + 16 * mi + 4 * g + r;
                    int b = m >> 11, ll = m & (L_ - 1);
                    float rv0 = fract_((float)ll * invr0);
                    float rv1 = fract_((float)ll * invr1);
                    float s0 = sin_rev(rv0), c0 = cos_rev(rv0);
                    float s1 = sin_rev(rv1), c1 = cos_rev(rv1);
                    size_t rb = ((size_t)(b * H_ + h) * L_ + ll) * DH_;
                    float a1 = acc[mi][0][r], a2 = acc[mi][2][r];   // dh=ln, ln+32
                    base[rb + ln]      = f2bf((a1 * c0 - a2 * s0) * scale);
                    base[rb + ln + 32] = f2bf((a2 * c0 + a1 * s0) * scale);
                    float b1 = acc[mi][1][r], b2 = acc[mi][3][r];   // dh=16+ln, 48+ln
                    base[rb + 16 + ln]      = f2bf((b1 * c1 - b2 * s1) * scale);
                    base[rb + 16 + ln + 32] = f2bf((b2 * c1 + b1 * s1) * scale);
                }
            }
        }
    }
}

// ---------------------------------------------------------------------------
// Flash attention v7 (unchanged from R9): shared LDS staging, counted vmcnt,
// raw barriers + compiler fences, swapped QK^T, defer-max, packed P,
// KVBLK=128 (two 64-key sub-tiles per barrier pair).
// Layouts: A: lane holds A[ln][32kk+8g+j]; B: lane holds Bt[ln][32kk+8g+j];
//          D: lane reg r -> D[4g+r][ln]   (g=lane>>4, ln=lane&15)
// ---------------------------------------------------------------------------
__global__ __launch_bounds__(256)
void attn_mfma(const ushort_t* __restrict__ qb, const ushort_t* __restrict__ kb,
               const ushort_t* __restrict__ vt, ushort_t* __restrict__ ao)
{
    __shared__ ushort_t Ks[2][128 * 64];    // [key][d], 128B rows, swizzled
    __shared__ ushort_t Vs[2][64 * 128];    // [d][key], 256B rows, swizzled
    __shared__ ushort_t Ps[4][32 * 64];     // per-wave P [32 q][64 key], swizzled

    const int t    = threadIdx.x;
    const int lane = t & 63, wv = t >> 6;
    const int g    = lane >> 4, ln = lane & 15;
    const int bh   = blockIdx.x;
    const int q0   = blockIdx.y * 128 + wv * 32;

    // Q fragments: half h covers rows q0+16h+ln
    const ushort_t* qpA = qb + ((size_t)bh * L_ + q0 + ln) * DH_;
    bf16x8 qf[2][2];
    qf[0][0] = *(const bf16x8*)(qpA + 8 * g);
    qf[0][1] = *(const bf16x8*)(qpA + 32 + 8 * g);
    qf[1][0] = *(const bf16x8*)(qpA + 16 * DH_ + 8 * g);
    qf[1][1] = *(const bf16x8*)(qpA + 16 * DH_ + 32 + 8 * g);

    const ushort_t* kp = kb + (size_t)bh * L_ * DH_;
    const ushort_t* vp = vt + (size_t)bh * DH_ * L_;

    // K staging: issue i covers tile rows 32wv+8i..+8 (row&7 = lane>>3)
    const int krow8 = lane >> 3;
    const int ksch  = (lane & 7) ^ krow8;
    // V staging: issue i covers d-rows 16wv+4i..+4 (row&7 = (4i+lane>>4)&7)
    const int vrow4 = lane >> 4;

    char* Pw = (char*)&Ps[wv][0];           // half h at byte offset 2048*h
    const int swz = (ln & 7) << 4;

    f32x4 O[2][4];
    #pragma unroll
    for (int h = 0; h < 2; ++h)
        #pragma unroll
        for (int n = 0; n < 4; ++n) O[h][n] = f32x4{0.f, 0.f, 0.f, 0.f};
    float m_q[2] = {-INFINITY, -INFINITY}, l_q[2] = {0.f, 0.f};

    auto stage = [&](int tt, int buf) {
        #pragma unroll
        for (int i = 0; i < 4; ++i) {
            int row = 32 * wv + 8 * i + krow8;
            gload16(kp + ((size_t)(tt * 128 + row)) * 64 + ksch * 8,
                    &Ks[buf][(32 * wv + 8 * i) * 64]);
        }
        #pragma unroll
        for (int i = 0; i < 4; ++i) {
            int row  = 16 * wv + 4 * i + vrow4;
            int vsch = (lane & 15) ^ ((4 * i + vrow4) & 7);
            gload16(vp + ((size_t)row) * L_ + tt * 128 + vsch * 8,
                    &Vs[buf][(16 * wv + 4 * i) * 128]);
        }
    };

    auto process = [&](const ushort_t* Kc, const ushort_t* Vc, int sub) {
        // ---- swapped QK^T: S[h][n][r] = S^T[key=64sub+16n+4g+r][q=16h+ln] ----
        f32x4 S[2][4];
        #pragma unroll
        for (int h = 0; h < 2; ++h)
            #pragma unroll
            for (int n = 0; n < 4; ++n) S[h][n] = f32x4{0.f, 0.f, 0.f, 0.f};
        #pragma unroll
        for (int kk = 0; kk < 2; ++kk) {
            bf16x8 kfv[4];
            #pragma unroll
            for (int n = 0; n < 4; ++n) {
                int row  = 64 * sub + 16 * n + ln;      // row&7 == ln&7
                int phys = (4 * kk + g) ^ (ln & 7);
                kfv[n] = *(const bf16x8*)&Kc[row * 64 + phys * 8];
            }
            __builtin_amdgcn_s_setprio(1);
            #pragma unroll
            for (int n = 0; n < 4; ++n) S[0][n] = MFMA16(kfv[n], qf[0][kk], S[0][n]);
            #pragma unroll
            for (int n = 0; n < 4; ++n) S[1][n] = MFMA16(kfv[n], qf[1][kk], S[1][n]);
            __builtin_amdgcn_s_setprio(0);
        }

        // ---- softmax per half (q = 16h + ln) ----
        #pragma unroll
        for (int h = 0; h < 2; ++h) {
            float pmax;
            {
                float a0 = fmaxf(fmaxf(S[h][0][0], S[h][0][1]), fmaxf(S[h][0][2], S[h][0][3]));
                float a1 = fmaxf(fmaxf(S[h][1][0], S[h][1][1]), fmaxf(S[h][1][2], S[h][1][3]));
                float a2 = fmaxf(fmaxf(S[h][2][0], S[h][2][1]), fmaxf(S[h][2][2], S[h][2][3]));
                float a3 = fmaxf(fmaxf(S[h][3][0], S[h][3][1]), fmaxf(S[h][3][2], S[h][3][3]));
                pmax = fmaxf(fmaxf(a0, a1), fmaxf(a2, a3));
            }
            pmax = fmaxf(pmax, __shfl_xor(pmax, 16));
            pmax = fmaxf(pmax, __shfl_xor(pmax, 32));

            if (!__all(pmax - m_q[h] <= 8.0f)) {   // defer-max (T13)
                float mnew = fmaxf(m_q[h], pmax);
                float al   = exp2_(m_q[h] - mnew);
                m_q[h] = mnew;
                l_q[h] *= al;
                #pragma unroll
                for (int r = 0; r < 4; ++r) {
                    float alr = bperm_f((4 * g + r) * 4, al);
                    #pragma unroll
                    for (int n = 0; n < 4; ++n) O[h][n][r] *= alr;
                }
            }

            float psum = 0.f;
            #pragma unroll
            for (int n = 0; n < 4; ++n) {
                float p0 = exp2_(S[h][n][0] - m_q[h]);
                float p1 = exp2_(S[h][n][1] - m_q[h]);
                float p2 = exp2_(S[h][n][2] - m_q[h]);
                float p3 = exp2_(S[h][n][3] - m_q[h]);
                psum += (p0 + p1) + (p2 + p3);
                uintx2 wq;
                wq[0] = cvtpk(p0, p1);
                wq[1] = cvtpk(p2, p3);
                *(uintx2*)(Pw + 2048 * h + 128 * ln + ((32 * n + 8 * g) ^ swz)) = wq;
            }
            psum += __shfl_xor(psum, 16);
            psum += __shfl_xor(psum, 32);
            l_q[h] += psum;
        }

        // ---- PV (P wave-private; same-wave DS in-order; no barrier) ----
        #pragma unroll
        for (int kk = 0; kk < 2; ++kk) {
            bf16x8 vfv[4];
            #pragma unroll
            for (int n = 0; n < 4; ++n) {
                int row  = 16 * n + ln;                 // row&7 == ln&7
                int phys = 8 * sub + ((4 * kk + g) ^ (ln & 7));
                vfv[n] = *(const bf16x8*)&Vc[row * 128 + phys * 8];
            }
            bf16x8 pa0 = *(const bf16x8*)(Pw + 128 * ln + ((64 * kk + 16 * g) ^ swz));
            bf16x8 pa1 = *(const bf16x8*)(Pw + 2048 + 128 * ln + ((64 * kk + 16 * g) ^ swz));
            __builtin_amdgcn_s_setprio(1);
            #pragma unroll
            for (int n = 0; n < 4; ++n) O[0][n] = MFMA16(pa0, vfv[n], O[0][n]);
            #pragma unroll
            for (int n = 0; n < 4; ++n) O[1][n] = MFMA16(pa1, vfv[n], O[1][n]);
            __builtin_amdgcn_s_setprio(0);
        }
    };

    stage(0, 0);
    for (int tt = 0; tt < L_ / 128; ++tt) {
        const int cur = tt & 1, nxt = cur ^ 1;
        const int nk  = (tt < L_ / 128 - 1) ? tt + 1 : tt;  // clamp: redundant reload
        stage(nk, nxt);
        asm volatile("s_waitcnt vmcnt(8)" ::: "memory");  // my tile-tt loads landed
        __builtin_amdgcn_s_barrier();                      // landed for ALL waves
        asm volatile("" ::: "memory");   // fence: no LDS reads above the barrier
        process(&Ks[cur][0], &Vs[cur][0], 0);
        process(&Ks[cur][0], &Vs[cur][0], 1);
        __builtin_amdgcn_s_barrier();    // all waves done reading buf[cur]
        asm volatile("" ::: "memory");   // fence: next staging stays below
    }
    asm volatile("s_waitcnt vmcnt(0)" ::: "memory");  // drain redundant tail loads

    // epilogue: pull l for q=16h+4g+r, normalize, write bf16 ao [B][L][D]
    const int b = bh >> 4, hh = bh & 15;
    #pragma unroll
    for (int h = 0; h < 2; ++h) {
        #pragma unroll
        for (int r = 0; r < 4; ++r) {
            float lb  = bperm_f((4 * g + r) * 4, l_q[h]);
            float inv = 1.0f / lb;
            int ql = q0 + 16 * h + 4 * g + r;
            ushort_t* dst = ao + ((size_t)(b * L_ + ql)) * D_ + hh * 64;
            #pragma unroll
            for (int n = 0; n < 4; ++n)
                dst[16 * n + ln] = f2bf(O[h][n][r] * inv);
        }
    }
}

// ---------------------------------------------------------------------------
extern "C" void kernel_launch(void* const* d_in, const int* in_sizes, int n_in,
                              void* d_out, int out_size, void* d_ws, size_t ws_size,
                              hipStream_t stream)
{
    const float* x    = (const float*)d_in[0];
    const float* Wqkv = (const float*)d_in[1];
    const float* Wo   = (const float*)d_in[2];
    float* out = (float*)d_out;

    char* ws = (char*)d_ws;                               // 64 MB layout:
    ushort_t* xb  = (ushort_t*)(ws);                      // [0,8M)   x bf16; later ao
    ushort_t* wqt = (ushort_t*)(ws + ((size_t) 8 << 20)); // [8,14M)  Wqkv^T bf16
    ushort_t* wot = (ushort_t*)(ws + ((size_t)14 << 20)); // [14,16M) Wo^T bf16
    ushort_t* qR  = (ushort_t*)(ws + ((size_t)16 << 20)); // [16,24M) q rope'd (from GEMM)
    ushort_t* kR  = (ushort_t*)(ws + ((size_t)24 << 20)); // [24,32M) k rope'd (from GEMM)
    ushort_t* vt  = (ushort_t*)(ws + ((size_t)32 << 20)); // [32,40M) v^T (from GEMM)
    ushort_t* ao  = xb;                                   // alias (xb dead post-gemm)

    convert_x<<<(M_ * D_) / (8 * 256), 256, 0, stream>>>(x, xb);
    transpose_w<N1_><<<dim3(N1_ / 64, 16), 256, 0, stream>>>(Wqkv, wqt);
    transpose_w<D_ ><<<dim3(D_  / 64, 16), 256, 0, stream>>>(Wo, wot);

    bgemm<1><<<dim3(N1_ / 128, M_ / 128), 256, 0, stream>>>(xb, wqt, nullptr, qR, kR, vt);
    attn_mfma<<<dim3(B_ * H_, L_ / 128), 256, 0, stream>>>(qR, kR, vt, ao);
    bgemm<0><<<dim3(D_ / 128, M_ / 128), 256, 0, stream>>>(ao, wot, out, nullptr, nullptr, nullptr);
}

// Round 11
// 137.009 us; speedup vs baseline: 1.5068x; 1.0564x over previous
//
#include <hip/hip_runtime.h>
#include <hip/hip_bf16.h>

#define B_  2
#define L_  2048
#define D_  1024
#define H_  16
#define DH_ 64
#define M_  (B_*L_)     // 4096
#define N1_ (3*D_)      // 3072

#define QSCALE (0.125f * 1.44269504088896340736f)   // 1/sqrt(64) * log2(e)

typedef __bf16 bf16x8 __attribute__((ext_vector_type(8)));
typedef float  f32x4  __attribute__((ext_vector_type(4)));
typedef unsigned short ushort_t;
typedef unsigned short ushort8_t __attribute__((ext_vector_type(8)));
typedef unsigned int   uintx2    __attribute__((ext_vector_type(2)));

#define MFMA16(a,b,c) __builtin_amdgcn_mfma_f32_16x16x32_bf16((a),(b),(c),0,0,0)

__device__ __forceinline__ float4 ld4(const float* p) { return *(const float4*)p; }

__device__ __forceinline__ ushort_t f2bf(float f) {
    union { float f; unsigned int u; } v; v.f = f;
    unsigned int r = (v.u + 0x7FFFu + ((v.u >> 16) & 1u)) >> 16;
    return (ushort_t)r;
}
__device__ __forceinline__ float bf2f(ushort_t u) {
    union { unsigned int u; float f; } v; v.u = ((unsigned int)u) << 16;
    return v.f;
}
// v_exp_f32 computes 2^x
__device__ __forceinline__ float exp2_(float x) {
    float r; asm("v_exp_f32 %0, %1" : "=v"(r) : "v"(x)); return r;
}
// hardware trig: input in REVOLUTIONS, reduce with v_fract first (ISA §3)
__device__ __forceinline__ float fract_(float x) {
    float r; asm("v_fract_f32 %0, %1" : "=v"(r) : "v"(x)); return r;
}
__device__ __forceinline__ float sin_rev(float x) {
    float r; asm("v_sin_f32 %0, %1" : "=v"(r) : "v"(x)); return r;
}
__device__ __forceinline__ float cos_rev(float x) {
    float r; asm("v_cos_f32 %0, %1" : "=v"(r) : "v"(x)); return r;
}
// packed f32 pair -> bf16 pair (lo = a, hi = b)
__device__ __forceinline__ unsigned cvtpk(float a, float b) {
    unsigned r; asm("v_cvt_pk_bf16_f32 %0, %1, %2" : "=v"(r) : "v"(a), "v"(b)); return r;
}
// pull float from lane (byte_addr = src_lane*4)
__device__ __forceinline__ float bperm_f(int byte_addr, float v) {
    union { float f; int i; } u; u.f = v;
    u.i = __builtin_amdgcn_ds_bpermute(byte_addr, u.i);
    return u.f;
}
// async global->LDS, 16B per lane; LDS dest = wave-uniform base + lane*16
__device__ __forceinline__ void gload16(const ushort_t* g, ushort_t* l) {
    __builtin_amdgcn_global_load_lds(
        (const __attribute__((address_space(1))) unsigned int*)g,
        (__attribute__((address_space(3))) unsigned int*)l, 16, 0, 0);
}

// ---------------------------------------------------------------------------
// x fp32 -> bf16, elementwise, 8/thread
// ---------------------------------------------------------------------------
__global__ __launch_bounds__(256)
void convert_x(const float* __restrict__ in, ushort_t* __restrict__ out)
{
    int i = (blockIdx.x * 256 + threadIdx.x) * 8;
    float4 a = ld4(in + i), b = ld4(in + i + 4);
    ushort8_t o;
    o[0] = f2bf(a.x); o[1] = f2bf(a.y); o[2] = f2bf(a.z); o[3] = f2bf(a.w);
    o[4] = f2bf(b.x); o[5] = f2bf(b.y); o[6] = f2bf(b.z); o[7] = f2bf(b.w);
    *(ushort8_t*)(out + i) = o;
}

// ---------------------------------------------------------------------------
// W fp32 [1024][N] -> bf16 W^T [N][1024], 64x64 LDS tiles
// ---------------------------------------------------------------------------
template<int N>
__global__ __launch_bounds__(256)
void transpose_w(const float* __restrict__ in, ushort_t* __restrict__ out)
{
    __shared__ float vs[64][65];
    const int nt = blockIdx.x, kt = blockIdx.y, t = threadIdx.x;
    #pragma unroll
    for (int i = 0; i < 4; ++i) {
        int idx = t + 256 * i;
        int row = idx >> 4, c4 = idx & 15;
        float4 x4 = ld4(in + (size_t)(kt * 64 + row) * N + nt * 64 + c4 * 4);
        vs[row][c4*4+0] = x4.x; vs[row][c4*4+1] = x4.y;
        vs[row][c4*4+2] = x4.z; vs[row][c4*4+3] = x4.w;
    }
    __syncthreads();
    #pragma unroll
    for (int i = 0; i < 16; ++i) {
        int idx = t + 256 * i;
        int nc = idx >> 6, kc = idx & 63;
        out[(size_t)(nt * 64 + nc) * 1024 + kt * 64 + kc] = f2bf(vs[kc][nc]);
    }
}

// ---------------------------------------------------------------------------
// bf16 MFMA GEMM, m97 structure, tile BM x 128 (BM = 128 or 64).
// EPI 0: fp32 C. EPI 1 (BM=128): QKV scatter with fused RoPE on Q,K and
// V written transposed (vt [bh][64 d][L]).
// ---------------------------------------------------------------------------
template<int EPI, int BM>
__global__ __launch_bounds__(256)
void bgemm(const ushort_t* __restrict__ A, const ushort_t* __restrict__ Bt,
           float* __restrict__ Cf,
           ushort_t* __restrict__ Qo, ushort_t* __restrict__ Ko, ushort_t* __restrict__ Vo)
{
    constexpr int K  = 1024;
    constexpr int MI = BM / 32;             // acc rows per wave (4 or 2)
    __shared__ ushort_t As[BM * 64];
    __shared__ ushort_t Bs[128 * 64];
    const int t  = threadIdx.x;
    const int l  = t & 63, w = t >> 6;
    const int g  = l >> 4, ln = l & 15;
    const int wr = w >> 1, wc = w & 1;
    const int m0 = blockIdx.y * BM, n0 = blockIdx.x * 128;

    const int srow = w * 8 + (l >> 3);
    const int sch  = (l & 7) ^ (l >> 3);
    const ushort_t* Ag = A  + ((size_t)(m0 + srow)) * K + sch * 8;
    const ushort_t* Bg = Bt + ((size_t)(n0 + srow)) * K + sch * 8;

    f32x4 acc[MI][4];
    #pragma unroll
    for (int mi = 0; mi < MI; ++mi)
        #pragma unroll
        for (int nj = 0; nj < 4; ++nj) acc[mi][nj] = f32x4{0.f, 0.f, 0.f, 0.f};

    for (int kt = 0; kt < K / 64; ++kt) {
        #pragma unroll
        for (int i = 0; i < BM / 32; ++i)
            gload16(Ag + (size_t)i * 32 * K + kt * 64, &As[i * 2048 + w * 512]);
        #pragma unroll
        for (int i = 0; i < 4; ++i)
            gload16(Bg + (size_t)i * 32 * K + kt * 64, &Bs[i * 2048 + w * 512]);
        __syncthreads();

        #pragma unroll
        for (int kk = 0; kk < 2; ++kk) {
            bf16x8 af[MI], bfv[4];
            #pragma unroll
            for (int mi = 0; mi < MI; ++mi) {
                int row  = (BM / 2) * wr + 16 * mi + ln;
                int phys = (4 * kk + g) ^ (ln & 7);
                af[mi] = *(const bf16x8*)&As[row * 64 + phys * 8];
            }
            #pragma unroll
            for (int nj = 0; nj < 4; ++nj) {
                int row  = 64 * wc + 16 * nj + ln;
                int phys = (4 * kk + g) ^ (ln & 7);
                bfv[nj] = *(const bf16x8*)&Bs[row * 64 + phys * 8];
            }
            #pragma unroll
            for (int mi = 0; mi < MI; ++mi)
                #pragma unroll
                for (int nj = 0; nj < 4; ++nj)
                    acc[mi][nj] = MFMA16(af[mi], bfv[nj], acc[mi][nj]);
        }
        __syncthreads();
    }

    if (EPI == 0) {
        #pragma unroll
        for (int mi = 0; mi < MI; ++mi) {
            #pragma unroll
            for (int nj = 0; nj < 4; ++nj) {
                int n = n0 + 64 * wc + 16 * nj + ln;
                #pragma unroll
                for (int r = 0; r < 4; ++r) {
                    int m = m0 + (BM / 2) * wr + 16 * mi + 4 * g + r;
                    Cf[(size_t)m * D_ + n] = acc[mi][nj][r];
                }
            }
        }
    } else {
        // all four nj share one 64-column block -> same (which, head)
        const int nb    = n0 + 64 * wc;
        const int which = nb >> 10;
        const int h     = (nb >> 6) & (H_ - 1);
        if (which == 2) {           // V: transposed scatter [bh][d][L]
            #pragma unroll
            for (int mi = 0; mi < MI; ++mi)
                #pragma unroll
                for (int nj = 0; nj < 4; ++nj) {
                    int dh = 16 * nj + ln;
                    #pragma unroll
                    for (int r = 0; r < 4; ++r) {
                        int m = m0 + (BM / 2) * wr + 16 * mi + 4 * g + r;
                        int b = m >> 11, ll = m & (L_ - 1);
                        Vo[((size_t)(b * H_ + h) * DH_ + dh) * L_ + ll] = f2bf(acc[mi][nj][r]);
                    }
                }
        } else {                    // Q or K: fused RoPE (pairs nj & nj+2)
            ushort_t* base = (which == 0) ? Qo : Ko;
            const float scale = (which == 0) ? QSCALE : 1.0f;
            // inv = 10000^(-j/32) via 2^(-j*log2(1e4)/32); pre-divide by 2pi
            const float invr0 = exp2_(-(float)ln        * 0.41524101186f) * 0.15915494310f;
            const float invr1 = exp2_(-(float)(16 + ln) * 0.41524101186f) * 0.15915494310f;
            #pragma unroll
            for (int mi = 0; mi < MI; ++mi) {
                #pragma unroll
                for (int r = 0; r < 4; ++r) {
                    int m = m0 + (BM / 2) * wr + 16 * mi + 4 * g + r;
                    int b = m >> 11, ll = m & (L_ - 1);
                    float rv0 = fract_((float)ll * invr0);
                    float rv1 = fract_((float)ll * invr1);
                    float s0 = sin_rev(rv0), c0 = cos_rev(rv0);
                    float s1 = sin_rev(rv1), c1 = cos_rev(rv1);
                    size_t rb = ((size_t)(b * H_ + h) * L_ + ll) * DH_;
                    float a1 = acc[mi][0][r], a2 = acc[mi][2][r];   // dh=ln, ln+32
                    base[rb + ln]      = f2bf((a1 * c0 - a2 * s0) * scale);
                    base[rb + ln + 32] = f2bf((a2 * c0 + a1 * s0) * scale);
                    float b1 = acc[mi][1][r], b2 = acc[mi][3][r];   // dh=16+ln, 48+ln
                    base[rb + 16 + ln]      = f2bf((b1 * c1 - b2 * s1) * scale);
                    base[rb + 16 + ln + 32] = f2bf((b2 * c1 + b1 * s1) * scale);
                }
            }
        }
    }
}

// ---------------------------------------------------------------------------
// Flash attention v8: SINGLE-buffered K/V staging (m97 pattern: stage ->
// __syncthreads -> compute -> __syncthreads), LDS 48KB -> 3 blocks/CU
// (R5/R9 showed dbuf+counted-vmcnt bought ~0 at 2 blocks/CU; trade prefetch
// for +50% TLP, cross-block overlap hides the drain per m114).
// Swapped QK^T, defer-max, packed P, KVBLK=128 (two 64-key sub-tiles).
// Layouts: A: lane holds A[ln][32kk+8g+j]; B: lane holds Bt[ln][32kk+8g+j];
//          D: lane reg r -> D[4g+r][ln]   (g=lane>>4, ln=lane&15)
// ---------------------------------------------------------------------------
__global__ __launch_bounds__(256)
void attn_mfma(const ushort_t* __restrict__ qb, const ushort_t* __restrict__ kb,
               const ushort_t* __restrict__ vt, ushort_t* __restrict__ ao)
{
    __shared__ ushort_t Ks[128 * 64];       // [key][d], 128B rows, swizzled
    __shared__ ushort_t Vs[64 * 128];       // [d][key], 256B rows, swizzled
    __shared__ ushort_t Ps[4][32 * 64];     // per-wave P [32 q][64 key], swizzled

    const int t    = threadIdx.x;
    const int lane = t & 63, wv = t >> 6;
    const int g    = lane >> 4, ln = lane & 15;
    const int bh   = blockIdx.x;
    const int q0   = blockIdx.y * 128 + wv * 32;

    // Q fragments: half h covers rows q0+16h+ln
    const ushort_t* qpA = qb + ((size_t)bh * L_ + q0 + ln) * DH_;
    bf16x8 qf[2][2];
    qf[0][0] = *(const bf16x8*)(qpA + 8 * g);
    qf[0][1] = *(const bf16x8*)(qpA + 32 + 8 * g);
    qf[1][0] = *(const bf16x8*)(qpA + 16 * DH_ + 8 * g);
    qf[1][1] = *(const bf16x8*)(qpA + 16 * DH_ + 32 + 8 * g);

    const ushort_t* kp = kb + (size_t)bh * L_ * DH_;
    const ushort_t* vp = vt + (size_t)bh * DH_ * L_;

    // K staging: issue i covers tile rows 32wv+8i..+8 (row&7 = lane>>3)
    const int krow8 = lane >> 3;
    const int ksch  = (lane & 7) ^ krow8;
    // V staging: issue i covers d-rows 16wv+4i..+4 (row&7 = (4i+lane>>4)&7)
    const int vrow4 = lane >> 4;

    char* Pw = (char*)&Ps[wv][0];           // half h at byte offset 2048*h
    const int swz = (ln & 7) << 4;

    f32x4 O[2][4];
    #pragma unroll
    for (int h = 0; h < 2; ++h)
        #pragma unroll
        for (int n = 0; n < 4; ++n) O[h][n] = f32x4{0.f, 0.f, 0.f, 0.f};
    float m_q[2] = {-INFINITY, -INFINITY}, l_q[2] = {0.f, 0.f};

    auto stage = [&](int tt) {
        #pragma unroll
        for (int i = 0; i < 4; ++i) {
            int row = 32 * wv + 8 * i + krow8;
            gload16(kp + ((size_t)(tt * 128 + row)) * 64 + ksch * 8,
                    &Ks[(32 * wv + 8 * i) * 64]);
        }
        #pragma unroll
        for (int i = 0; i < 4; ++i) {
            int row  = 16 * wv + 4 * i + vrow4;
            int vsch = (lane & 15) ^ ((4 * i + vrow4) & 7);
            gload16(vp + ((size_t)row) * L_ + tt * 128 + vsch * 8,
                    &Vs[(16 * wv + 4 * i) * 128]);
        }
    };

    auto process = [&](int sub) {
        // ---- swapped QK^T: S[h][n][r] = S^T[key=64sub+16n+4g+r][q=16h+ln] ----
        f32x4 S[2][4];
        #pragma unroll
        for (int h = 0; h < 2; ++h)
            #pragma unroll
            for (int n = 0; n < 4; ++n) S[h][n] = f32x4{0.f, 0.f, 0.f, 0.f};
        #pragma unroll
        for (int kk = 0; kk < 2; ++kk) {
            bf16x8 kfv[4];
            #pragma unroll
            for (int n = 0; n < 4; ++n) {
                int row  = 64 * sub + 16 * n + ln;      // row&7 == ln&7
                int phys = (4 * kk + g) ^ (ln & 7);
                kfv[n] = *(const bf16x8*)&Ks[row * 64 + phys * 8];
            }
            __builtin_amdgcn_s_setprio(1);
            #pragma unroll
            for (int n = 0; n < 4; ++n) S[0][n] = MFMA16(kfv[n], qf[0][kk], S[0][n]);
            #pragma unroll
            for (int n = 0; n < 4; ++n) S[1][n] = MFMA16(kfv[n], qf[1][kk], S[1][n]);
            __builtin_amdgcn_s_setprio(0);
        }

        // ---- softmax per half (q = 16h + ln) ----
        #pragma unroll
        for (int h = 0; h < 2; ++h) {
            float pmax;
            {
                float a0 = fmaxf(fmaxf(S[h][0][0], S[h][0][1]), fmaxf(S[h][0][2], S[h][0][3]));
                float a1 = fmaxf(fmaxf(S[h][1][0], S[h][1][1]), fmaxf(S[h][1][2], S[h][1][3]));
                float a2 = fmaxf(fmaxf(S[h][2][0], S[h][2][1]), fmaxf(S[h][2][2], S[h][2][3]));
                float a3 = fmaxf(fmaxf(S[h][3][0], S[h][3][1]), fmaxf(S[h][3][2], S[h][3][3]));
                pmax = fmaxf(fmaxf(a0, a1), fmaxf(a2, a3));
            }
            pmax = fmaxf(pmax, __shfl_xor(pmax, 16));
            pmax = fmaxf(pmax, __shfl_xor(pmax, 32));

            if (!__all(pmax - m_q[h] <= 8.0f)) {   // defer-max (T13)
                float mnew = fmaxf(m_q[h], pmax);
                float al   = exp2_(m_q[h] - mnew);
                m_q[h] = mnew;
                l_q[h] *= al;
                #pragma unroll
                for (int r = 0; r < 4; ++r) {
                    float alr = bperm_f((4 * g + r) * 4, al);
                    #pragma unroll
                    for (int n = 0; n < 4; ++n) O[h][n][r] *= alr;
                }
            }

            float psum = 0.f;
            #pragma unroll
            for (int n = 0; n < 4; ++n) {
                float p0 = exp2_(S[h][n][0] - m_q[h]);
                float p1 = exp2_(S[h][n][1] - m_q[h]);
                float p2 = exp2_(S[h][n][2] - m_q[h]);
                float p3 = exp2_(S[h][n][3] - m_q[h]);
                psum += (p0 + p1) + (p2 + p3);
                uintx2 wq;
                wq[0] = cvtpk(p0, p1);
                wq[1] = cvtpk(p2, p3);
                *(uintx2*)(Pw + 2048 * h + 128 * ln + ((32 * n + 8 * g) ^ swz)) = wq;
            }
            psum += __shfl_xor(psum, 16);
            psum += __shfl_xor(psum, 32);
            l_q[h] += psum;
        }

        // ---- PV (P wave-private; same-wave DS in-order; no barrier) ----
        #pragma unroll
        for (int kk = 0; kk < 2; ++kk) {
            bf16x8 vfv[4];
            #pragma unroll
            for (int n = 0; n < 4; ++n) {
                int row  = 16 * n + ln;                 // row&7 == ln&7
                int phys = 8 * sub + ((4 * kk + g) ^ (ln & 7));
                vfv[n] = *(const bf16x8*)&Vs[row * 128 + phys * 8];
            }
            bf16x8 pa0 = *(const bf16x8*)(Pw + 128 * ln + ((64 * kk + 16 * g) ^ swz));
            bf16x8 pa1 = *(const bf16x8*)(Pw + 2048 + 128 * ln + ((64 * kk + 16 * g) ^ swz));
            __builtin_amdgcn_s_setprio(1);
            #pragma unroll
            for (int n = 0; n < 4; ++n) O[0][n] = MFMA16(pa0, vfv[n], O[0][n]);
            #pragma unroll
            for (int n = 0; n < 4; ++n) O[1][n] = MFMA16(pa1, vfv[n], O[1][n]);
            __builtin_amdgcn_s_setprio(0);
        }
    };

    for (int tt = 0; tt < L_ / 128; ++tt) {
        stage(tt);
        __syncthreads();    // drains vmcnt(0): tile tt fully in LDS, all waves
        process(0);
        process(1);
        __syncthreads();    // all waves done reading before next stage
    }

    // epilogue: pull l for q=16h+4g+r, normalize, write bf16 ao [B][L][D]
    const int b = bh >> 4, hh = bh & 15;
    #pragma unroll
    for (int h = 0; h < 2; ++h) {
        #pragma unroll
        for (int r = 0; r < 4; ++r) {
            float lb  = bperm_f((4 * g + r) * 4, l_q[h]);
            float inv = 1.0f / lb;
            int ql = q0 + 16 * h + 4 * g + r;
            ushort_t* dst = ao + ((size_t)(b * L_ + ql)) * D_ + hh * 64;
            #pragma unroll
            for (int n = 0; n < 4; ++n)
                dst[16 * n + ln] = f2bf(O[h][n][r] * inv);
        }
    }
}

// ---------------------------------------------------------------------------
extern "C" void kernel_launch(void* const* d_in, const int* in_sizes, int n_in,
                              void* d_out, int out_size, void* d_ws, size_t ws_size,
                              hipStream_t stream)
{
    const float* x    = (const float*)d_in[0];
    const float* Wqkv = (const float*)d_in[1];
    const float* Wo   = (const float*)d_in[2];
    float* out = (float*)d_out;

    char* ws = (char*)d_ws;                               // 64 MB layout:
    ushort_t* xb  = (ushort_t*)(ws);                      // [0,8M)   x bf16; later ao
    ushort_t* wqt = (ushort_t*)(ws + ((size_t) 8 << 20)); // [8,14M)  Wqkv^T bf16
    ushort_t* wot = (ushort_t*)(ws + ((size_t)14 << 20)); // [14,16M) Wo^T bf16
    ushort_t* qR  = (ushort_t*)(ws + ((size_t)16 << 20)); // [16,24M) q rope'd (from GEMM)
    ushort_t* kR  = (ushort_t*)(ws + ((size_t)24 << 20)); // [24,32M) k rope'd (from GEMM)
    ushort_t* vt  = (ushort_t*)(ws + ((size_t)32 << 20)); // [32,40M) v^T (from GEMM)
    ushort_t* ao  = xb;                                   // alias (xb dead post-gemm)

    convert_x<<<(M_ * D_) / (8 * 256), 256, 0, stream>>>(x, xb);
    transpose_w<N1_><<<dim3(N1_ / 64, 16), 256, 0, stream>>>(Wqkv, wqt);
    transpose_w<D_ ><<<dim3(D_  / 64, 16), 256, 0, stream>>>(Wo, wot);

    bgemm<1, 128><<<dim3(N1_ / 128, M_ / 128), 256, 0, stream>>>(xb, wqt, nullptr, qR, kR, vt);
    attn_mfma<<<dim3(B_ * H_, L_ / 128), 256, 0, stream>>>(qR, kR, vt, ao);
    bgemm<0, 64><<<dim3(D_ / 128, M_ / 64), 256, 0, stream>>>(ao, wot, out, nullptr, nullptr, nullptr);
}

// Round 12
// 129.470 us; speedup vs baseline: 1.5946x; 1.0582x over previous
//
#include <hip/hip_runtime.h>
#include <hip/hip_bf16.h>

#define B_  2
#define L_  2048
#define D_  1024
#define H_  16
#define DH_ 64
#define M_  (B_*L_)     // 4096
#define N1_ (3*D_)      // 3072

#define QSCALE (0.125f * 1.44269504088896340736f)   // 1/sqrt(64) * log2(e)

typedef __bf16 bf16x8 __attribute__((ext_vector_type(8)));
typedef float  f32x4  __attribute__((ext_vector_type(4)));
typedef unsigned short ushort_t;
typedef unsigned short ushort8_t __attribute__((ext_vector_type(8)));
typedef unsigned int   uintx2    __attribute__((ext_vector_type(2)));

#define MFMA16(a,b,c) __builtin_amdgcn_mfma_f32_16x16x32_bf16((a),(b),(c),0,0,0)

__device__ __forceinline__ float4 ld4(const float* p) { return *(const float4*)p; }

__device__ __forceinline__ ushort_t f2bf(float f) {
    union { float f; unsigned int u; } v; v.f = f;
    unsigned int r = (v.u + 0x7FFFu + ((v.u >> 16) & 1u)) >> 16;
    return (ushort_t)r;
}
__device__ __forceinline__ float bf2f(ushort_t u) {
    union { unsigned int u; float f; } v; v.u = ((unsigned int)u) << 16;
    return v.f;
}
// v_exp_f32 computes 2^x
__device__ __forceinline__ float exp2_(float x) {
    float r; asm("v_exp_f32 %0, %1" : "=v"(r) : "v"(x)); return r;
}
// hardware trig: input in REVOLUTIONS, reduce with v_fract first (ISA §3)
__device__ __forceinline__ float fract_(float x) {
    float r; asm("v_fract_f32 %0, %1" : "=v"(r) : "v"(x)); return r;
}
__device__ __forceinline__ float sin_rev(float x) {
    float r; asm("v_sin_f32 %0, %1" : "=v"(r) : "v"(x)); return r;
}
__device__ __forceinline__ float cos_rev(float x) {
    float r; asm("v_cos_f32 %0, %1" : "=v"(r) : "v"(x)); return r;
}
// packed f32 pair -> bf16 pair (lo = a, hi = b)
__device__ __forceinline__ unsigned cvtpk(float a, float b) {
    unsigned r; asm("v_cvt_pk_bf16_f32 %0, %1, %2" : "=v"(r) : "v"(a), "v"(b)); return r;
}
// pull float from lane (byte_addr = src_lane*4)
__device__ __forceinline__ float bperm_f(int byte_addr, float v) {
    union { float f; int i; } u; u.f = v;
    u.i = __builtin_amdgcn_ds_bpermute(byte_addr, u.i);
    return u.f;
}
// async global->LDS, 16B per lane; LDS dest = wave-uniform base + lane*16
__device__ __forceinline__ void gload16(const ushort_t* g, ushort_t* l) {
    __builtin_amdgcn_global_load_lds(
        (const __attribute__((address_space(1))) unsigned int*)g,
        (__attribute__((address_space(3))) unsigned int*)l, 16, 0, 0);
}

// ---------------------------------------------------------------------------
// Fused prep: blocks [0,2048) x fp32->bf16; [2048,2816) Wqkv^T; [2816,3072) Wo^T
// ---------------------------------------------------------------------------
__global__ __launch_bounds__(256)
void prep(const float* __restrict__ x, const float* __restrict__ Wqkv,
          const float* __restrict__ Wo,
          ushort_t* __restrict__ xb, ushort_t* __restrict__ wqt,
          ushort_t* __restrict__ wot)
{
    __shared__ float vs[64][65];
    const int bid = blockIdx.x, t = threadIdx.x;
    if (bid < 2048) {
        int i = (bid * 256 + t) * 8;
        float4 a = ld4(x + i), b = ld4(x + i + 4);
        ushort8_t o;
        o[0] = f2bf(a.x); o[1] = f2bf(a.y); o[2] = f2bf(a.z); o[3] = f2bf(a.w);
        o[4] = f2bf(b.x); o[5] = f2bf(b.y); o[6] = f2bf(b.z); o[7] = f2bf(b.w);
        *(ushort8_t*)(xb + i) = o;
        return;
    }
    const float* in; ushort_t* out; int nt, kt, N;
    if (bid < 2048 + 768) {
        in = Wqkv; out = wqt; N = N1_;
        nt = (bid - 2048) % 48; kt = (bid - 2048) / 48;
    } else {
        in = Wo; out = wot; N = D_;
        nt = (bid - 2816) % 16; kt = (bid - 2816) / 16;
    }
    #pragma unroll
    for (int i = 0; i < 4; ++i) {
        int idx = t + 256 * i;
        int row = idx >> 4, c4 = idx & 15;
        float4 x4 = ld4(in + (size_t)(kt * 64 + row) * N + nt * 64 + c4 * 4);
        vs[row][c4*4+0] = x4.x; vs[row][c4*4+1] = x4.y;
        vs[row][c4*4+2] = x4.z; vs[row][c4*4+3] = x4.w;
    }
    __syncthreads();
    #pragma unroll
    for (int i = 0; i < 16; ++i) {
        int idx = t + 256 * i;
        int nc = idx >> 6, kc = idx & 63;
        out[(size_t)(nt * 64 + nc) * 1024 + kt * 64 + kc] = f2bf(vs[kc][nc]);
    }
}

// ---------------------------------------------------------------------------
// bf16 MFMA GEMM, m97 structure, tile BM x 128 (BM = 128 or 64).
// EPI 0: fp32 C. EPI 1 (BM=128): QKV scatter with fused RoPE on Q,K and
// V written transposed (vt [bh][64 d][L]).
// ---------------------------------------------------------------------------
template<int EPI, int BM>
__global__ __launch_bounds__(256)
void bgemm(const ushort_t* __restrict__ A, const ushort_t* __restrict__ Bt,
           float* __restrict__ Cf,
           ushort_t* __restrict__ Qo, ushort_t* __restrict__ Ko, ushort_t* __restrict__ Vo)
{
    constexpr int K  = 1024;
    constexpr int MI = BM / 32;             // acc rows per wave (4 or 2)
    __shared__ ushort_t As[BM * 64];
    __shared__ ushort_t Bs[128 * 64];
    const int t  = threadIdx.x;
    const int l  = t & 63, w = t >> 6;
    const int g  = l >> 4, ln = l & 15;
    const int wr = w >> 1, wc = w & 1;
    const int m0 = blockIdx.y * BM, n0 = blockIdx.x * 128;

    const int srow = w * 8 + (l >> 3);
    const int sch  = (l & 7) ^ (l >> 3);
    const ushort_t* Ag = A  + ((size_t)(m0 + srow)) * K + sch * 8;
    const ushort_t* Bg = Bt + ((size_t)(n0 + srow)) * K + sch * 8;

    f32x4 acc[MI][4];
    #pragma unroll
    for (int mi = 0; mi < MI; ++mi)
        #pragma unroll
        for (int nj = 0; nj < 4; ++nj) acc[mi][nj] = f32x4{0.f, 0.f, 0.f, 0.f};

    for (int kt = 0; kt < K / 64; ++kt) {
        #pragma unroll
        for (int i = 0; i < BM / 32; ++i)
            gload16(Ag + (size_t)i * 32 * K + kt * 64, &As[i * 2048 + w * 512]);
        #pragma unroll
        for (int i = 0; i < 4; ++i)
            gload16(Bg + (size_t)i * 32 * K + kt * 64, &Bs[i * 2048 + w * 512]);
        __syncthreads();

        #pragma unroll
        for (int kk = 0; kk < 2; ++kk) {
            bf16x8 af[MI], bfv[4];
            #pragma unroll
            for (int mi = 0; mi < MI; ++mi) {
                int row  = (BM / 2) * wr + 16 * mi + ln;
                int phys = (4 * kk + g) ^ (ln & 7);
                af[mi] = *(const bf16x8*)&As[row * 64 + phys * 8];
            }
            #pragma unroll
            for (int nj = 0; nj < 4; ++nj) {
                int row  = 64 * wc + 16 * nj + ln;
                int phys = (4 * kk + g) ^ (ln & 7);
                bfv[nj] = *(const bf16x8*)&Bs[row * 64 + phys * 8];
            }
            #pragma unroll
            for (int mi = 0; mi < MI; ++mi)
                #pragma unroll
                for (int nj = 0; nj < 4; ++nj)
                    acc[mi][nj] = MFMA16(af[mi], bfv[nj], acc[mi][nj]);
        }
        __syncthreads();
    }

    if (EPI == 0) {
        #pragma unroll
        for (int mi = 0; mi < MI; ++mi) {
            #pragma unroll
            for (int nj = 0; nj < 4; ++nj) {
                int n = n0 + 64 * wc + 16 * nj + ln;
                #pragma unroll
                for (int r = 0; r < 4; ++r) {
                    int m = m0 + (BM / 2) * wr + 16 * mi + 4 * g + r;
                    Cf[(size_t)m * D_ + n] = acc[mi][nj][r];
                }
            }
        }
    } else {
        // all four nj share one 64-column block -> same (which, head)
        const int nb    = n0 + 64 * wc;
        const int which = nb >> 10;
        const int h     = (nb >> 6) & (H_ - 1);
        if (which == 2) {           // V: transposed scatter [bh][d][L]
            #pragma unroll
            for (int mi = 0; mi < MI; ++mi)
                #pragma unroll
                for (int nj = 0; nj < 4; ++nj) {
                    int dh = 16 * nj + ln;
                    #pragma unroll
                    for (int r = 0; r < 4; ++r) {
                        int m = m0 + (BM / 2) * wr + 16 * mi + 4 * g + r;
                        int b = m >> 11, ll = m & (L_ - 1);
                        Vo[((size_t)(b * H_ + h) * DH_ + dh) * L_ + ll] = f2bf(acc[mi][nj][r]);
                    }
                }
        } else {                    // Q or K: fused RoPE (pairs nj & nj+2)
            ushort_t* base = (which == 0) ? Qo : Ko;
            const float scale = (which == 0) ? QSCALE : 1.0f;
            // inv = 10000^(-j/32) via 2^(-j*log2(1e4)/32); pre-divide by 2pi
            const float invr0 = exp2_(-(float)ln        * 0.41524101186f) * 0.15915494310f;
            const float invr1 = exp2_(-(float)(16 + ln) * 0.41524101186f) * 0.15915494310f;
            #pragma unroll
            for (int mi = 0; mi < MI; ++mi) {
                #pragma unroll
                for (int r = 0; r < 4; ++r) {
                    int m = m0 + (BM / 2) * wr + 16 * mi + 4 * g + r;
                    int b = m >> 11, ll = m & (L_ - 1);
                    float rv0 = fract_((float)ll * invr0);
                    float rv1 = fract_((float)ll * invr1);
                    float s0 = sin_rev(rv0), c0 = cos_rev(rv0);
                    float s1 = sin_rev(rv1), c1 = cos_rev(rv1);
                    size_t rb = ((size_t)(b * H_ + h) * L_ + ll) * DH_;
                    float a1 = acc[mi][0][r], a2 = acc[mi][2][r];   // dh=ln, ln+32
                    base[rb + ln]      = f2bf((a1 * c0 - a2 * s0) * scale);
                    base[rb + ln + 32] = f2bf((a2 * c0 + a1 * s0) * scale);
                    float b1 = acc[mi][1][r], b2 = acc[mi][3][r];   // dh=16+ln, 48+ln
                    base[rb + 16 + ln]      = f2bf((b1 * c1 - b2 * s1) * scale);
                    base[rb + 16 + ln + 32] = f2bf((b2 * c1 + b1 * s1) * scale);
                }
            }
        }
    }
}

// ---------------------------------------------------------------------------
// Flash attention v9 (v8 + VALU cuts):
//  - bias-in-accumulator: QK^T acc init = -m (m is a base-2 bias, init 0;
//    defer-max keeps per-tile pmax <= 8) -> p = exp2(S) directly, the
//    subtract runs only in the rare trigger branch.
//  - l via ones-MFMA: lacc = MFMA(P_frag, ones, lacc) accumulates the
//    softmax denominator in D-layout (q=4g+r) - exactly the epilogue's
//    lanes; removes psum adds + shuffles + epilogue bpermutes. l is
//    computed from the rounded bf16 P, matching the PV numerator.
// Structure otherwise = R11: single-buffer staging, swapped QK^T, packed P.
// Layouts: A: lane holds A[ln][32kk+8g+j]; B: lane holds Bt[ln][32kk+8g+j];
//          D: lane reg r -> D[4g+r][ln]   (g=lane>>4, ln=lane&15)
// ---------------------------------------------------------------------------
__global__ __launch_bounds__(256)
void attn_mfma(const ushort_t* __restrict__ qb, const ushort_t* __restrict__ kb,
               const ushort_t* __restrict__ vt, ushort_t* __restrict__ ao)
{
    __shared__ ushort_t Ks[128 * 64];       // [key][d], 128B rows, swizzled
    __shared__ ushort_t Vs[64 * 128];       // [d][key], 256B rows, swizzled
    __shared__ ushort_t Ps[4][32 * 64];     // per-wave P [32 q][64 key], swizzled

    const int t    = threadIdx.x;
    const int lane = t & 63, wv = t >> 6;
    const int g    = lane >> 4, ln = lane & 15;
    const int bh   = blockIdx.x;
    const int q0   = blockIdx.y * 128 + wv * 32;

    // Q fragments: half h covers rows q0+16h+ln
    const ushort_t* qpA = qb + ((size_t)bh * L_ + q0 + ln) * DH_;
    bf16x8 qf[2][2];
    qf[0][0] = *(const bf16x8*)(qpA + 8 * g);
    qf[0][1] = *(const bf16x8*)(qpA + 32 + 8 * g);
    qf[1][0] = *(const bf16x8*)(qpA + 16 * DH_ + 8 * g);
    qf[1][1] = *(const bf16x8*)(qpA + 16 * DH_ + 32 + 8 * g);

    const ushort_t* kp = kb + (size_t)bh * L_ * DH_;
    const ushort_t* vp = vt + (size_t)bh * DH_ * L_;

    // ones B-fragment for the l-accumulating MFMA
    union { ushort8_t u; bf16x8 v; } onesu;
    #pragma unroll
    for (int j = 0; j < 8; ++j) onesu.u[j] = 0x3F80;   // bf16 1.0
    const bf16x8 onesf = onesu.v;

    // K staging: issue i covers tile rows 32wv+8i..+8 (row&7 = lane>>3)
    const int krow8 = lane >> 3;
    const int ksch  = (lane & 7) ^ krow8;
    // V staging: issue i covers d-rows 16wv+4i..+4 (row&7 = (4i+lane>>4)&7)
    const int vrow4 = lane >> 4;

    char* Pw = (char*)&Ps[wv][0];           // half h at byte offset 2048*h
    const int swz = (ln & 7) << 4;

    f32x4 O[2][4], lacc[2];
    #pragma unroll
    for (int h = 0; h < 2; ++h) {
        lacc[h] = f32x4{0.f, 0.f, 0.f, 0.f};
        #pragma unroll
        for (int n = 0; n < 4; ++n) O[h][n] = f32x4{0.f, 0.f, 0.f, 0.f};
    }
    float m_q[2] = {0.f, 0.f};              // base-2 bias (not -inf: see theory)

    auto stage = [&](int tt) {
        #pragma unroll
        for (int i = 0; i < 4; ++i) {
            int row = 32 * wv + 8 * i + krow8;
            gload16(kp + ((size_t)(tt * 128 + row)) * 64 + ksch * 8,
                    &Ks[(32 * wv + 8 * i) * 64]);
        }
        #pragma unroll
        for (int i = 0; i < 4; ++i) {
            int row  = 16 * wv + 4 * i + vrow4;
            int vsch = (lane & 15) ^ ((4 * i + vrow4) & 7);
            gload16(vp + ((size_t)row) * L_ + tt * 128 + vsch * 8,
                    &Vs[(16 * wv + 4 * i) * 128]);
        }
    };

    auto process = [&](int sub) {
        // ---- swapped QK^T, acc pre-biased by -m ----
        f32x4 S[2][4];
        #pragma unroll
        for (int h = 0; h < 2; ++h)
            #pragma unroll
            for (int n = 0; n < 4; ++n)
                S[h][n] = f32x4{-m_q[h], -m_q[h], -m_q[h], -m_q[h]};
        #pragma unroll
        for (int kk = 0; kk < 2; ++kk) {
            bf16x8 kfv[4];
            #pragma unroll
            for (int n = 0; n < 4; ++n) {
                int row  = 64 * sub + 16 * n + ln;      // row&7 == ln&7
                int phys = (4 * kk + g) ^ (ln & 7);
                kfv[n] = *(const bf16x8*)&Ks[row * 64 + phys * 8];
            }
            __builtin_amdgcn_s_setprio(1);
            #pragma unroll
            for (int n = 0; n < 4; ++n) S[0][n] = MFMA16(kfv[n], qf[0][kk], S[0][n]);
            #pragma unroll
            for (int n = 0; n < 4; ++n) S[1][n] = MFMA16(kfv[n], qf[1][kk], S[1][n]);
            __builtin_amdgcn_s_setprio(0);
        }

        // ---- softmax per half (q = 16h + ln); S is already S_true - m ----
        #pragma unroll
        for (int h = 0; h < 2; ++h) {
            float pmax;
            {
                float a0 = fmaxf(fmaxf(S[h][0][0], S[h][0][1]), fmaxf(S[h][0][2], S[h][0][3]));
                float a1 = fmaxf(fmaxf(S[h][1][0], S[h][1][1]), fmaxf(S[h][1][2], S[h][1][3]));
                float a2 = fmaxf(fmaxf(S[h][2][0], S[h][2][1]), fmaxf(S[h][2][2], S[h][2][3]));
                float a3 = fmaxf(fmaxf(S[h][3][0], S[h][3][1]), fmaxf(S[h][3][2], S[h][3][3]));
                pmax = fmaxf(fmaxf(a0, a1), fmaxf(a2, a3));
            }
            pmax = fmaxf(pmax, __shfl_xor(pmax, 16));
            pmax = fmaxf(pmax, __shfl_xor(pmax, 32));

            if (!__all(pmax <= 8.0f)) {     // defer-max trigger (rare)
                m_q[h] += pmax;
                float al = exp2_(-pmax);
                #pragma unroll
                for (int r = 0; r < 4; ++r) {
                    float alr = bperm_f((4 * g + r) * 4, al);
                    lacc[h][r] *= alr;
                    #pragma unroll
                    for (int n = 0; n < 4; ++n) O[h][n][r] *= alr;
                }
                #pragma unroll
                for (int n = 0; n < 4; ++n) S[h][n] = S[h][n] - pmax;
            }

            #pragma unroll
            for (int n = 0; n < 4; ++n) {
                float p0 = exp2_(S[h][n][0]);
                float p1 = exp2_(S[h][n][1]);
                float p2 = exp2_(S[h][n][2]);
                float p3 = exp2_(S[h][n][3]);
                uintx2 wq;
                wq[0] = cvtpk(p0, p1);
                wq[1] = cvtpk(p2, p3);
                *(uintx2*)(Pw + 2048 * h + 128 * ln + ((32 * n + 8 * g) ^ swz)) = wq;
            }
        }

        // ---- PV + l accumulation (P wave-private; same-wave DS in-order) ----
        #pragma unroll
        for (int kk = 0; kk < 2; ++kk) {
            bf16x8 vfv[4];
            #pragma unroll
            for (int n = 0; n < 4; ++n) {
                int row  = 16 * n + ln;                 // row&7 == ln&7
                int phys = 8 * sub + ((4 * kk + g) ^ (ln & 7));
                vfv[n] = *(const bf16x8*)&Vs[row * 128 + phys * 8];
            }
            bf16x8 pa0 = *(const bf16x8*)(Pw + 128 * ln + ((64 * kk + 16 * g) ^ swz));
            bf16x8 pa1 = *(const bf16x8*)(Pw + 2048 + 128 * ln + ((64 * kk + 16 * g) ^ swz));
            __builtin_amdgcn_s_setprio(1);
            #pragma unroll
            for (int n = 0; n < 4; ++n) O[0][n] = MFMA16(pa0, vfv[n], O[0][n]);
            #pragma unroll
            for (int n = 0; n < 4; ++n) O[1][n] = MFMA16(pa1, vfv[n], O[1][n]);
            lacc[0] = MFMA16(pa0, onesf, lacc[0]);
            lacc[1] = MFMA16(pa1, onesf, lacc[1]);
            __builtin_amdgcn_s_setprio(0);
        }
    };

    for (int tt = 0; tt < L_ / 128; ++tt) {
        stage(tt);
        __syncthreads();    // drains vmcnt(0): tile tt fully in LDS, all waves
        process(0);
        process(1);
        __syncthreads();    // all waves done reading before next stage
    }

    // epilogue: lacc[h][r] IS l for q=16h+4g+r; normalize, write bf16 ao
    const int b = bh >> 4, hh = bh & 15;
    #pragma unroll
    for (int h = 0; h < 2; ++h) {
        #pragma unroll
        for (int r = 0; r < 4; ++r) {
            float inv = 1.0f / lacc[h][r];
            int ql = q0 + 16 * h + 4 * g + r;
            ushort_t* dst = ao + ((size_t)(b * L_ + ql)) * D_ + hh * 64;
            #pragma unroll
            for (int n = 0; n < 4; ++n)
                dst[16 * n + ln] = f2bf(O[h][n][r] * inv);
        }
    }
}

// ---------------------------------------------------------------------------
extern "C" void kernel_launch(void* const* d_in, const int* in_sizes, int n_in,
                              void* d_out, int out_size, void* d_ws, size_t ws_size,
                              hipStream_t stream)
{
    const float* x    = (const float*)d_in[0];
    const float* Wqkv = (const float*)d_in[1];
    const float* Wo   = (const float*)d_in[2];
    float* out = (float*)d_out;

    char* ws = (char*)d_ws;                               // 64 MB layout:
    ushort_t* xb  = (ushort_t*)(ws);                      // [0,8M)   x bf16; later ao
    ushort_t* wqt = (ushort_t*)(ws + ((size_t) 8 << 20)); // [8,14M)  Wqkv^T bf16
    ushort_t* wot = (ushort_t*)(ws + ((size_t)14 << 20)); // [14,16M) Wo^T bf16
    ushort_t* qR  = (ushort_t*)(ws + ((size_t)16 << 20)); // [16,24M) q rope'd (from GEMM)
    ushort_t* kR  = (ushort_t*)(ws + ((size_t)24 << 20)); // [24,32M) k rope'd (from GEMM)
    ushort_t* vt  = (ushort_t*)(ws + ((size_t)32 << 20)); // [32,40M) v^T (from GEMM)
    ushort_t* ao  = xb;                                   // alias (xb dead post-gemm)

    prep<<<3072, 256, 0, stream>>>(x, Wqkv, Wo, xb, wqt, wot);
    bgemm<1, 128><<<dim3(N1_ / 128, M_ / 128), 256, 0, stream>>>(xb, wqt, nullptr, qR, kR, vt);
    attn_mfma<<<dim3(B_ * H_, L_ / 128), 256, 0, stream>>>(qR, kR, vt, ao);
    bgemm<0, 64><<<dim3(D_ / 128, M_ / 64), 256, 0, stream>>>(ao, wot, out, nullptr, nullptr, nullptr);
}